// Round 2
// 827.948 us; speedup vs baseline: 1.4486x; 1.4486x over previous
//
#include <hip/hip_runtime.h>
#include <hip/hip_bf16.h>
#include <stdint.h>

// SparseMOE on MI355X (gfx950). Inputs/outputs FLOAT32.
// R5: R4 fast path with k_transp destination bug fixed (missing expert offset:
//     all 8 experts raced into the same transposed-weight region -> garbage
//     GEMM operands on the fast path). Fast path: pre-convert x/w1/w2/wo to
//     bf16 (weights transposed to [E][N][K]) once per launch, then both GEMMs
//     are pure-bf16 m97-template kernels: global_load_lds width-16 staging,
//     BK=64, chunk-XOR LDS swizzle (linear dest + inverse-swizzled global
//     source + swizzled ds_read, rule #21). Falls back to the R3 f32-staging
//     kernels (verified 1199 us) if workspace < ~295 MB.

#define T_TOKENS 4096
#define DM 1024
#define DH 4096
#define N_EXP 8
#define N_PAIRS (T_TOKENS * 2)
#define MAX_TILES 96             // worst-case sum ceil(N_e/128) = 71

typedef __hip_bfloat16 bf16_t;
typedef __bf16 bf16x8 __attribute__((ext_vector_type(8)));   // MFMA A/B frag (4 VGPRs)
typedef float  f32x4  __attribute__((ext_vector_type(4)));   // MFMA C/D frag
typedef unsigned short ushort4v __attribute__((ext_vector_type(4)));

// ---- workspace layout (byte offsets) ----
#define WS_COUNTS   0        // int[8]   tokens per expert
#define WS_OFFSETS  32       // int[8]   exclusive scan
#define WS_PSUM     96       // float[8] sum of probs per expert
#define WS_NTILES   128      // int
#define WS_CURSOR   192      // int[8]   slot-assignment cursors (k_fill)
#define WS_TILE_E   256      // int[128] tile -> expert
#define WS_TILE_M0  768      // int[128] tile -> first slot
#define WS_E_OF     4096     // int[8192]   (t,k) -> expert
#define WS_W_OF     69632    // float[8192] (t,k) -> gate weight
#define WS_TOK_OF   102400   // int[8192]   slot -> token
#define WS_WT_OF    135168   // float[8192] slot -> gate weight
#define WS_SLOT_OF  167936   // int[8192]   (t,k) -> slot
#define WS_HBUF     (1u<<20)                              // bf16[8192][4096] = 64 MB
#define WS_YPAIR    (WS_HBUF + (size_t)N_PAIRS*DH*2)      // bf16[8192][1024] = 16 MB
#define WS_NEEDED   (WS_YPAIR + (size_t)N_PAIRS*DM*2)     // ~81 MB (fallback path)
// fast path: bf16 pre-converted operands
#define WS_XBF      WS_NEEDED                             // bf16[4096][1024] = 8 MB
#define WS_W1T      (WS_XBF + (size_t)T_TOKENS*DM*2)      // bf16[E][DH][DM] = 64 MB
#define WS_W2T      (WS_W1T + (size_t)N_EXP*DM*DH*2)      // bf16[E][DH][DM] = 64 MB
#define WS_WOT      (WS_W2T + (size_t)N_EXP*DM*DH*2)      // bf16[E][DM][DH] = 64 MB
#define WS_NEEDED_BIG (WS_WOT + (size_t)N_EXP*DM*DH*2)    // ~295 MB

#define PITCH 40   // LDS row pitch for fallback kernels

__device__ __forceinline__ unsigned short f2bf(float f) {
  bf16_t h = __float2bfloat16(f);   // RNE
  return *(unsigned short*)&h;
}

// async global->LDS, 16 B per lane. LDS dest = wave-uniform base + lane*16.
__device__ __forceinline__ void gload16(const void* g, void* l) {
  __builtin_amdgcn_global_load_lds(
      (const __attribute__((address_space(1))) unsigned int*)g,
      (__attribute__((address_space(3))) unsigned int*)l, 16, 0, 0);
}

// ---------------- router: 64 blocks x 256 thr; wave handles 16 tokens ----------------
#define RT_BLOCKS 64
#define RT_TPB (T_TOKENS / RT_BLOCKS)   // 64 tokens per block
#define RT_TPW (RT_TPB / 4)             // 16 tokens per wave

__global__ __launch_bounds__(256) void k_router(const float* __restrict__ x,
                                                const float* __restrict__ rw,
                                                const float* __restrict__ rb,
                                                char* __restrict__ ws) {
  __shared__ float s_psum[4][8];
  __shared__ unsigned long long s_hist[4];
  int tid = threadIdx.x, lane = tid & 63, wave = tid >> 6;
  int t0 = blockIdx.x * RT_TPB + wave * RT_TPW;
  int* e_of = (int*)(ws + WS_E_OF);
  float* w_of = (float*)(ws + WS_W_OF);

  float lpsum[8];
#pragma unroll
  for (int e = 0; e < 8; ++e) lpsum[e] = 0.f;
  unsigned long long lhist = 0ull;

  for (int tt = 0; tt < RT_TPW; ++tt) {
    int t = t0 + tt;
    float acc[8];
#pragma unroll
    for (int e = 0; e < 8; ++e) acc[e] = 0.f;
    const float* xr = x + (size_t)t * DM;
    for (int j = lane; j < DM; j += 64) {
      float xv = xr[j];
      float4 r01 = *(const float4*)(rw + j * 8);
      float4 r23 = *(const float4*)(rw + j * 8 + 4);
      acc[0] += xv * r01.x; acc[1] += xv * r01.y;
      acc[2] += xv * r01.z; acc[3] += xv * r01.w;
      acc[4] += xv * r23.x; acc[5] += xv * r23.y;
      acc[6] += xv * r23.z; acc[7] += xv * r23.w;
    }
#pragma unroll
    for (int m = 1; m < 64; m <<= 1) {
#pragma unroll
      for (int e = 0; e < 8; ++e) acc[e] += __shfl_xor(acc[e], m);
    }
    float mx = -1e30f;
#pragma unroll
    for (int e = 0; e < 8; ++e) { acc[e] += rb[e]; mx = fmaxf(mx, acc[e]); }
    float s = 0.f;
#pragma unroll
    for (int e = 0; e < 8; ++e) { acc[e] = __expf(acc[e] - mx); s += acc[e]; }
    float inv = 1.f / s;
#pragma unroll
    for (int e = 0; e < 8; ++e) { acc[e] *= inv; lpsum[e] += acc[e]; }
    int i1 = 0;
#pragma unroll
    for (int e = 1; e < 8; ++e) if (acc[e] > acc[i1]) i1 = e;
    int i2 = -1;
#pragma unroll
    for (int e = 0; e < 8; ++e) if (e != i1 && (i2 < 0 || acc[e] > acc[i2])) i2 = e;
    lhist += (1ull << (i1 * 8)) + (1ull << (i2 * 8));
    if (lane == 0) {
      e_of[2 * t] = i1; e_of[2 * t + 1] = i2;
      w_of[2 * t] = acc[i1]; w_of[2 * t + 1] = acc[i2];
    }
  }
  if (lane == 0) {
#pragma unroll
    for (int e = 0; e < 8; ++e) s_psum[wave][e] = lpsum[e];
    s_hist[wave] = lhist;
  }
  __syncthreads();
  if (tid < 8) {
    float p = s_psum[0][tid] + s_psum[1][tid] + s_psum[2][tid] + s_psum[3][tid];
    atomicAdd((float*)(ws + WS_PSUM) + tid, p);
    int c = 0;
#pragma unroll
    for (int w = 0; w < 4; ++w) c += (int)((s_hist[w] >> (tid * 8)) & 0xff);
    atomicAdd((int*)(ws + WS_COUNTS) + tid, c);
  }
}

// ---------------- scan: offsets, tile table, lb_loss ----------------
__global__ void k_scan(char* __restrict__ ws, float* __restrict__ out) {
  if (threadIdx.x == 0 && blockIdx.x == 0) {
    int* counts = (int*)(ws + WS_COUNTS);
    int* offs = (int*)(ws + WS_OFFSETS);
    int* te = (int*)(ws + WS_TILE_E);
    int* tm = (int*)(ws + WS_TILE_M0);
    int off = 0, nt = 0;
    for (int e = 0; e < 8; ++e) {
      offs[e] = off;
      for (int m0 = 0; m0 < counts[e]; m0 += 128) { te[nt] = e; tm[nt] = off + m0; ++nt; }
      off += counts[e];
    }
    *(int*)(ws + WS_NTILES) = nt;
    float* psum = (float*)(ws + WS_PSUM);
    float lb = 0.f;
    for (int e = 0; e < 8; ++e)
      lb += ((float)counts[e] / (float)T_TOKENS) * (psum[e] / (float)T_TOKENS);
    lb *= 0.01f * 8.f;
    out[(size_t)T_TOKENS * DM] = lb;
  }
}

// ---------------- fill: (t,k) -> slot via block-level ranking ----------------
__global__ __launch_bounds__(256) void k_fill(char* __restrict__ ws) {
  __shared__ int hist[8];
  __shared__ int base[8];
  int tid = threadIdx.x;
  int i = blockIdx.x * 256 + tid;
  if (tid < 8) hist[tid] = 0;
  __syncthreads();
  int e = ((const int*)(ws + WS_E_OF))[i];
  int rank = atomicAdd(&hist[e], 1);
  __syncthreads();
  if (tid < 8) base[tid] = atomicAdd((int*)(ws + WS_CURSOR) + tid, hist[tid]);
  __syncthreads();
  int slot = ((const int*)(ws + WS_OFFSETS))[e] + base[e] + rank;
  ((int*)(ws + WS_TOK_OF))[slot] = i >> 1;
  ((float*)(ws + WS_WT_OF))[slot] = ((const float*)(ws + WS_W_OF))[i];
  ((int*)(ws + WS_SLOT_OF))[i] = slot;
}

// ---------------- pre-pass: x f32 -> bf16 ----------------
__global__ __launch_bounds__(256) void k_cvt_x(const float* __restrict__ x,
                                               char* __restrict__ ws) {
  int i = blockIdx.x * 256 + threadIdx.x;          // 8 elems each
  const float* s = x + (size_t)i * 8;
  float4 a = *(const float4*)s;
  float4 b = *(const float4*)(s + 4);
  uint4 v;
  v.x = (unsigned)f2bf(a.x) | ((unsigned)f2bf(a.y) << 16);
  v.y = (unsigned)f2bf(a.z) | ((unsigned)f2bf(a.w) << 16);
  v.z = (unsigned)f2bf(b.x) | ((unsigned)f2bf(b.y) << 16);
  v.w = (unsigned)f2bf(b.z) | ((unsigned)f2bf(b.w) << 16);
  *(uint4*)(ws + WS_XBF + (size_t)i * 16) = v;
}

// ---------------- pre-pass: transpose-convert [E][K][N] f32 -> [E][N][K] bf16 ------
// 64x64 tile per block, 256 threads. Read coalesced along N, write coalesced along K.
__global__ __launch_bounds__(256) void k_transp(const float* __restrict__ in,
                                                char* __restrict__ outc,
                                                int K, int N) {
  __shared__ __align__(16) float tile[64][68];   // pitch 68: 16B-aligned float4 rows
  int e = blockIdx.z;
  int k0 = blockIdx.y * 64, n0 = blockIdx.x * 64;
  int tid = threadIdx.x;
  const float* src = in + ((size_t)e * K + k0) * N + n0;
  int row = tid >> 2, c4 = (tid & 3) * 16;
#pragma unroll
  for (int j = 0; j < 4; ++j)
    *(float4*)&tile[row][c4 + j * 4] = *(const float4*)(src + (size_t)row * N + c4 + j * 4);
  __syncthreads();
  int n = tid >> 2, kc = (tid & 3) * 16;
  unsigned int pk[8];
#pragma unroll
  for (int j = 0; j < 8; ++j) {
    unsigned int lo = f2bf(tile[kc + 2 * j][n]);
    unsigned int hi = f2bf(tile[kc + 2 * j + 1][n]);
    pk[j] = lo | (hi << 16);
  }
  // R5 FIX: destination must include the expert offset (was racing all experts
  // into expert 0's region).
  char* dst = outc + ((size_t)e * K * N + (size_t)(n0 + n) * K + k0 + kc) * 2;
  uint4 v0 = {pk[0], pk[1], pk[2], pk[3]};
  uint4 v1 = {pk[4], pk[5], pk[6], pk[7]};
  *(uint4*)dst = v0;
  *(uint4*)(dst + 16) = v1;
}

// ---------------- GEMM1 (fast): H = (X@W1+b1) * silu(X@W2+b2), bf16 operands -------
// 256 thr = 4 waves (2x2), BM=128 tokens, BN=64 hidden cols (x2 matrices), BK=64.
// LDS linear [row][64] bf16 (128 B rows) staged via global_load_lds; chunk-XOR
// swizzle c'=c^(row&7) applied on the global SOURCE and on ds_read (rule #21).
__global__ __launch_bounds__(256, 2) void k_gemm1_bf(const float* __restrict__ b1,
                                                     const float* __restrict__ b2,
                                                     char* __restrict__ ws) {
  __shared__ __align__(16) unsigned short As[128 * 64];
  __shared__ __align__(16) unsigned short Bs1[64 * 64];
  __shared__ __align__(16) unsigned short Bs2[64 * 64];
  __shared__ int tokLds[128];
  int tid = threadIdx.x;
  int tileIdx = blockIdx.y;
  if (tileIdx >= *(const int*)(ws + WS_NTILES)) return;
  int e = ((const int*)(ws + WS_TILE_E))[tileIdx];
  int m_start = ((const int*)(ws + WS_TILE_M0))[tileIdx];
  int m_end = ((const int*)(ws + WS_OFFSETS))[e] + ((const int*)(ws + WS_COUNTS))[e];
  int m_cnt = min(128, m_end - m_start);
  int n0 = blockIdx.x * 64;
  if (tid < 128) tokLds[tid] = ((const int*)(ws + WS_TOK_OF))[m_start + min(tid, m_cnt - 1)];
  __syncthreads();

  int lane = tid & 63, wave = tid >> 6;
  int wm = wave >> 1, wn = wave & 1;
  int lr = lane & 15, quad = lane >> 4;
  int lsub = lane >> 3;           // row-sub within each 8-row staging group
  int clog = (lane & 7) ^ lsub;   // logical chunk this lane stages (inverse swizzle)

  const char* xbf = ws + WS_XBF;
  const char* w1t = ws + WS_W1T + (size_t)e * DM * DH * 2;
  const char* w2t = ws + WS_W2T + (size_t)e * DM * DH * 2;

  const char* srcA[4];
#pragma unroll
  for (int i = 0; i < 4; ++i) {
    int r = (wave * 4 + i) * 8 + lsub;   // row in [0,128)
    srcA[i] = xbf + (size_t)tokLds[r] * (DM * 2) + clog * 16;
  }
  const char* srcB1[2];
  const char* srcB2[2];
#pragma unroll
  for (int i = 0; i < 2; ++i) {
    int r = (wave * 2 + i) * 8 + lsub;   // row in [0,64)
    srcB1[i] = w1t + (size_t)(n0 + r) * (DM * 2) + clog * 16;
    srcB2[i] = w2t + (size_t)(n0 + r) * (DM * 2) + clog * 16;
  }

  f32x4 acc1[4][2], acc2[4][2];
  f32x4 z = {0.f, 0.f, 0.f, 0.f};
#pragma unroll
  for (int i = 0; i < 4; ++i)
#pragma unroll
    for (int j = 0; j < 2; ++j) { acc1[i][j] = z; acc2[i][j] = z; }

  for (int kt = 0; kt < DM / 64; ++kt) {
    int kb = kt * 128;   // byte advance per K-tile (64 bf16)
#pragma unroll
    for (int i = 0; i < 4; ++i)
      gload16(srcA[i] + kb, &As[(wave * 4 + i) * 512]);
#pragma unroll
    for (int i = 0; i < 2; ++i) {
      gload16(srcB1[i] + kb, &Bs1[(wave * 2 + i) * 512]);
      gload16(srcB2[i] + kb, &Bs2[(wave * 2 + i) * 512]);
    }
    __syncthreads();   // drains vmcnt(0): staged tile visible
#pragma unroll
    for (int s = 0; s < 2; ++s) {
      int sw = (((s * 4 + quad) ^ (lr & 7)) << 3);
      bf16x8 a[4], f1[2], f2v[2];
#pragma unroll
      for (int mt = 0; mt < 4; ++mt)
        a[mt] = *(const bf16x8*)&As[(wm * 64 + mt * 16 + lr) * 64 + sw];
#pragma unroll
      for (int nt = 0; nt < 2; ++nt) {
        int off = (wn * 32 + nt * 16 + lr) * 64 + sw;
        f1[nt]  = *(const bf16x8*)&Bs1[off];
        f2v[nt] = *(const bf16x8*)&Bs2[off];
      }
#pragma unroll
      for (int mt = 0; mt < 4; ++mt)
#pragma unroll
        for (int nt = 0; nt < 2; ++nt) {
          acc1[mt][nt] = __builtin_amdgcn_mfma_f32_16x16x32_bf16(a[mt], f1[nt],  acc1[mt][nt], 0, 0, 0);
          acc2[mt][nt] = __builtin_amdgcn_mfma_f32_16x16x32_bf16(a[mt], f2v[nt], acc2[mt][nt], 0, 0, 0);
        }
    }
    __syncthreads();   // compute done before next-tile overwrite
  }
  // epilogue: h = (t1+b1) * silu(t2+b2)  -> Hbuf bf16
  bf16_t* Hbuf = (bf16_t*)(ws + WS_HBUF);
#pragma unroll
  for (int mt = 0; mt < 4; ++mt) {
    int growb = wm * 64 + mt * 16 + quad * 4;   // C/D: row=(lane>>4)*4+reg, col=lane&15
#pragma unroll
    for (int nt = 0; nt < 2; ++nt) {
      int col = n0 + wn * 32 + nt * 16 + lr;
      float b1v = b1[e * DH + col];
      float b2v = b2[e * DH + col];
#pragma unroll
      for (int r = 0; r < 4; ++r) {
        int grow = growb + r;
        if (grow < m_cnt) {
          float v1 = acc1[mt][nt][r] + b1v;
          float v2 = acc2[mt][nt][r] + b2v;
          float hh = v1 * (v2 / (1.f + __expf(-v2)));
          Hbuf[(size_t)(m_start + grow) * DH + col] = __float2bfloat16(hh);
        }
      }
    }
  }
}

// ---------------- GEMM2 (fast): Y = wt * (H@wo + bo), bf16 operands ----------------
// 256 thr = 4 waves (2x2), BM=128 slots, BN=128 model cols, BK=64, K=4096.
__global__ __launch_bounds__(256, 2) void k_gemm2_bf(const float* __restrict__ bo,
                                                     char* __restrict__ ws) {
  __shared__ __align__(16) unsigned short As[128 * 64];
  __shared__ __align__(16) unsigned short Bs[128 * 64];
  int tid = threadIdx.x;
  int tileIdx = blockIdx.y;
  if (tileIdx >= *(const int*)(ws + WS_NTILES)) return;
  int e = ((const int*)(ws + WS_TILE_E))[tileIdx];
  int m_start = ((const int*)(ws + WS_TILE_M0))[tileIdx];
  int m_end = ((const int*)(ws + WS_OFFSETS))[e] + ((const int*)(ws + WS_COUNTS))[e];
  int m_cnt = min(128, m_end - m_start);
  int n0 = blockIdx.x * 128;

  int lane = tid & 63, wave = tid >> 6;
  int wm = wave >> 1, wn = wave & 1;
  int lr = lane & 15, quad = lane >> 4;
  int lsub = lane >> 3;
  int clog = (lane & 7) ^ lsub;

  const char* hb = ws + WS_HBUF;
  const char* wot = ws + WS_WOT + (size_t)e * DM * DH * 2;

  const char* srcA[4];
  const char* srcB[4];
#pragma unroll
  for (int i = 0; i < 4; ++i) {
    int r = (wave * 4 + i) * 8 + lsub;                  // row in [0,128)
    int hrow = m_start + min(r, m_cnt - 1);             // clamp: stay in written Hbuf
    srcA[i] = hb + (size_t)hrow * (DH * 2) + clog * 16;
    srcB[i] = wot + (size_t)(n0 + r) * (DH * 2) + clog * 16;
  }

  f32x4 acc[4][4];
  f32x4 z = {0.f, 0.f, 0.f, 0.f};
#pragma unroll
  for (int i = 0; i < 4; ++i)
#pragma unroll
    for (int j = 0; j < 4; ++j) acc[i][j] = z;

  for (int kt = 0; kt < DH / 64; ++kt) {
    int kb = kt * 128;
#pragma unroll
    for (int i = 0; i < 4; ++i) {
      gload16(srcA[i] + kb, &As[(wave * 4 + i) * 512]);
      gload16(srcB[i] + kb, &Bs[(wave * 4 + i) * 512]);
    }
    __syncthreads();
#pragma unroll
    for (int s = 0; s < 2; ++s) {
      int sw = (((s * 4 + quad) ^ (lr & 7)) << 3);
      bf16x8 a[4], b[4];
#pragma unroll
      for (int mt = 0; mt < 4; ++mt)
        a[mt] = *(const bf16x8*)&As[(wm * 64 + mt * 16 + lr) * 64 + sw];
#pragma unroll
      for (int nt = 0; nt < 4; ++nt)
        b[nt] = *(const bf16x8*)&Bs[(wn * 64 + nt * 16 + lr) * 64 + sw];
#pragma unroll
      for (int mt = 0; mt < 4; ++mt)
#pragma unroll
        for (int nt = 0; nt < 4; ++nt)
          acc[mt][nt] = __builtin_amdgcn_mfma_f32_16x16x32_bf16(a[mt], b[nt], acc[mt][nt], 0, 0, 0);
    }
    __syncthreads();
  }
  bf16_t* Ypair = (bf16_t*)(ws + WS_YPAIR);
  const float* wts = (const float*)(ws + WS_WT_OF);
#pragma unroll
  for (int mt = 0; mt < 4; ++mt) {
    int growb = wm * 64 + mt * 16 + quad * 4;
#pragma unroll
    for (int nt = 0; nt < 4; ++nt) {
      int col = n0 + wn * 64 + nt * 16 + lr;
      float bov = bo[e * DM + col];
#pragma unroll
      for (int r = 0; r < 4; ++r) {
        int grow = growb + r;
        if (grow < m_cnt) {
          int slot = m_start + grow;
          Ypair[(size_t)slot * DM + col] = __float2bfloat16((acc[mt][nt][r] + bov) * wts[slot]);
        }
      }
    }
  }
}

// ================= fallback (R3) GEMMs: f32 operands, reg-stage + cvt =================
__global__ __launch_bounds__(256, 2) void k_gemm1(const float* __restrict__ x,
                                                  const float* __restrict__ w1,
                                                  const float* __restrict__ b1,
                                                  const float* __restrict__ w2,
                                                  const float* __restrict__ b2,
                                                  char* __restrict__ ws) {
  __shared__ __align__(16) unsigned short As[128 * PITCH];
  __shared__ __align__(16) unsigned short Bs1[64 * PITCH];
  __shared__ __align__(16) unsigned short Bs2[64 * PITCH];
  __shared__ int tokLds[128];
  int tid = threadIdx.x;
  int tileIdx = blockIdx.y;
  if (tileIdx >= *(const int*)(ws + WS_NTILES)) return;
  int e = ((const int*)(ws + WS_TILE_E))[tileIdx];
  int m_start = ((const int*)(ws + WS_TILE_M0))[tileIdx];
  int m_end = ((const int*)(ws + WS_OFFSETS))[e] + ((const int*)(ws + WS_COUNTS))[e];
  int m_cnt = min(128, m_end - m_start);
  int n0 = blockIdx.x * 64;
  if (tid < 128) tokLds[tid] = ((const int*)(ws + WS_TOK_OF))[m_start + min(tid, m_cnt - 1)];
  __syncthreads();

  f32x4 acc1[4][2], acc2[4][2];
  f32x4 z = {0.f, 0.f, 0.f, 0.f};
#pragma unroll
  for (int i = 0; i < 4; ++i)
#pragma unroll
    for (int j = 0; j < 2; ++j) { acc1[i][j] = z; acc2[i][j] = z; }

  int lane = tid & 63, wave = tid >> 6;
  int wm = wave >> 1, wn = wave & 1;
  int lr = lane & 15, quad = lane >> 4;
  int q = tid & 127, mat = tid >> 7;
  int pk = (q & 15) * 2, pn = (q >> 4) * 8;
  const float* Wm = mat ? w2 : w1;
  unsigned short* BsM = mat ? Bs2 : Bs1;
  const float* bBase = Wm + ((size_t)e * DM + pk) * DH + n0 + pn;

  int aRow[4], aKc[4];
  const float* aPtr[4];
#pragma unroll
  for (int h = 0; h < 4; ++h) {
    int c = tid + h * 256;
    aRow[h] = c >> 3; aKc[h] = (c & 7) * 4;
    aPtr[h] = x + (size_t)tokLds[aRow[h]] * DM + aKc[h];
  }

  float4 aR[4], bR[4];
#define G1_LOAD(k0)                                                  \
  {                                                                  \
    _Pragma("unroll")                                                \
    for (int h = 0; h < 4; ++h) aR[h] = *(const float4*)(aPtr[h] + (k0)); \
    const float* src = bBase + (size_t)(k0) * DH;                    \
    bR[0] = *(const float4*)src;                                     \
    bR[1] = *(const float4*)(src + 4);                               \
    bR[2] = *(const float4*)(src + DH);                              \
    bR[3] = *(const float4*)(src + DH + 4);                          \
  }

  G1_LOAD(0);
  for (int kt = 0; kt < DM / 32; ++kt) {
    __syncthreads();
#pragma unroll
    for (int h = 0; h < 4; ++h) {
      ushort4v wv = { f2bf(aR[h].x), f2bf(aR[h].y), f2bf(aR[h].z), f2bf(aR[h].w) };
      *(ushort4v*)&As[aRow[h] * PITCH + aKc[h]] = wv;
    }
    {
      float av[8] = {bR[0].x, bR[0].y, bR[0].z, bR[0].w, bR[1].x, bR[1].y, bR[1].z, bR[1].w};
      float bv[8] = {bR[2].x, bR[2].y, bR[2].z, bR[2].w, bR[3].x, bR[3].y, bR[3].z, bR[3].w};
#pragma unroll
      for (int j = 0; j < 8; ++j) {
        unsigned int wv = (unsigned int)f2bf(av[j]) | ((unsigned int)f2bf(bv[j]) << 16);
        *(unsigned int*)&BsM[(pn + j) * PITCH + pk] = wv;
      }
    }
    __syncthreads();
    if (kt + 1 < DM / 32) G1_LOAD((kt + 1) * 32);
    bf16x8 a[4], f1[2], f2v[2];
#pragma unroll
    for (int mt = 0; mt < 4; ++mt)
      a[mt] = *(const bf16x8*)&As[(wm * 64 + mt * 16 + lr) * PITCH + quad * 8];
#pragma unroll
    for (int nt = 0; nt < 2; ++nt) {
      f1[nt]  = *(const bf16x8*)&Bs1[(wn * 32 + nt * 16 + lr) * PITCH + quad * 8];
      f2v[nt] = *(const bf16x8*)&Bs2[(wn * 32 + nt * 16 + lr) * PITCH + quad * 8];
    }
#pragma unroll
    for (int mt = 0; mt < 4; ++mt)
#pragma unroll
      for (int nt = 0; nt < 2; ++nt) {
        acc1[mt][nt] = __builtin_amdgcn_mfma_f32_16x16x32_bf16(a[mt], f1[nt],  acc1[mt][nt], 0, 0, 0);
        acc2[mt][nt] = __builtin_amdgcn_mfma_f32_16x16x32_bf16(a[mt], f2v[nt], acc2[mt][nt], 0, 0, 0);
      }
  }
  bf16_t* Hbuf = (bf16_t*)(ws + WS_HBUF);
#pragma unroll
  for (int mt = 0; mt < 4; ++mt) {
    int growb = wm * 64 + mt * 16 + quad * 4;
#pragma unroll
    for (int nt = 0; nt < 2; ++nt) {
      int col = n0 + wn * 32 + nt * 16 + lr;
      float b1v = b1[e * DH + col];
      float b2v = b2[e * DH + col];
#pragma unroll
      for (int r = 0; r < 4; ++r) {
        int grow = growb + r;
        if (grow < m_cnt) {
          float v1 = acc1[mt][nt][r] + b1v;
          float v2 = acc2[mt][nt][r] + b2v;
          float hh = v1 * (v2 / (1.f + __expf(-v2)));
          Hbuf[(size_t)(m_start + grow) * DH + col] = __float2bfloat16(hh);
        }
      }
    }
  }
}

__global__ __launch_bounds__(256, 2) void k_gemm2(const float* __restrict__ wo,
                                                  const float* __restrict__ bo,
                                                  char* __restrict__ ws) {
  __shared__ __align__(16) unsigned short As[128 * PITCH];
  __shared__ __align__(16) unsigned short Bs[128 * PITCH];
  int tid = threadIdx.x;
  int tileIdx = blockIdx.y;
  if (tileIdx >= *(const int*)(ws + WS_NTILES)) return;
  int e = ((const int*)(ws + WS_TILE_E))[tileIdx];
  int m_start = ((const int*)(ws + WS_TILE_M0))[tileIdx];
  int m_end = ((const int*)(ws + WS_OFFSETS))[e] + ((const int*)(ws + WS_COUNTS))[e];
  int m_cnt = min(128, m_end - m_start);
  int n0 = blockIdx.x * 128;
  const bf16_t* Hbuf = (const bf16_t*)(ws + WS_HBUF);

  f32x4 acc[4][4];
  f32x4 z = {0.f, 0.f, 0.f, 0.f};
#pragma unroll
  for (int i = 0; i < 4; ++i)
#pragma unroll
    for (int j = 0; j < 4; ++j) acc[i][j] = z;

  int lane = tid & 63, wave = tid >> 6;
  int wm = wave >> 1, wn = wave & 1;
  int lr = lane & 15, quad = lane >> 4;
  int pk = (tid & 15) * 2, pn = (tid >> 4) * 8;
  const float* bBase = wo + ((size_t)e * DH + pk) * DM + n0 + pn;

  int aRow[2], aKc[2];
  const bf16_t* aPtr[2];
#pragma unroll
  for (int h = 0; h < 2; ++h) {
    int c = tid + h * 256;
    aRow[h] = c >> 2; aKc[h] = (c & 3) * 8;
    int hrow = m_start + min(aRow[h], m_cnt - 1);
    aPtr[h] = Hbuf + (size_t)hrow * DH + aKc[h];
  }

  int4 aR[2]; float4 bR[4];
#define G2_LOAD(k0)                                                  \
  {                                                                  \
    _Pragma("unroll")                                                \
    for (int h = 0; h < 2; ++h) aR[h] = *(const int4*)(aPtr[h] + (k0)); \
    const float* src = bBase + (size_t)(k0) * DM;                    \
    bR[0] = *(const float4*)src;                                     \
    bR[1] = *(const float4*)(src + 4);                               \
    bR[2] = *(const float4*)(src + DM);                              \
    bR[3] = *(const float4*)(src + DM + 4);                          \
  }

  G2_LOAD(0);
  for (int kt = 0; kt < DH / 32; ++kt) {
    __syncthreads();
#pragma unroll
    for (int h = 0; h < 2; ++h)
      *(int4*)&As[aRow[h] * PITCH + aKc[h]] = aR[h];
    {
      float av[8] = {bR[0].x, bR[0].y, bR[0].z, bR[0].w, bR[1].x, bR[1].y, bR[1].z, bR[1].w};
      float bv[8] = {bR[2].x, bR[2].y, bR[2].z, bR[2].w, bR[3].x, bR[3].y, bR[3].z, bR[3].w};
#pragma unroll
      for (int j = 0; j < 8; ++j) {
        unsigned int wv = (unsigned int)f2bf(av[j]) | ((unsigned int)f2bf(bv[j]) << 16);
        *(unsigned int*)&Bs[(pn + j) * PITCH + pk] = wv;
      }
    }
    __syncthreads();
    if (kt + 1 < DH / 32) G2_LOAD((kt + 1) * 32);
    bf16x8 a[4], b[4];
#pragma unroll
    for (int mt = 0; mt < 4; ++mt)
      a[mt] = *(const bf16x8*)&As[(wm * 64 + mt * 16 + lr) * PITCH + quad * 8];
#pragma unroll
    for (int nt = 0; nt < 4; ++nt)
      b[nt] = *(const bf16x8*)&Bs[(wn * 64 + nt * 16 + lr) * PITCH + quad * 8];
#pragma unroll
    for (int mt = 0; mt < 4; ++mt)
#pragma unroll
      for (int nt = 0; nt < 4; ++nt)
        acc[mt][nt] = __builtin_amdgcn_mfma_f32_16x16x32_bf16(a[mt], b[nt], acc[mt][nt], 0, 0, 0);
  }
  bf16_t* Ypair = (bf16_t*)(ws + WS_YPAIR);
  const float* wts = (const float*)(ws + WS_WT_OF);
#pragma unroll
  for (int mt = 0; mt < 4; ++mt) {
    int growb = wm * 64 + mt * 16 + quad * 4;
#pragma unroll
    for (int nt = 0; nt < 4; ++nt) {
      int col = n0 + wn * 64 + nt * 16 + lr;
      float bov = bo[e * DM + col];
#pragma unroll
      for (int r = 0; r < 4; ++r) {
        int grow = growb + r;
        if (grow < m_cnt) {
          int slot = m_start + grow;
          Ypair[(size_t)slot * DM + col] = __float2bfloat16((acc[mt][nt][r] + bov) * wts[slot]);
        }
      }
    }
  }
}

// ---------------- combine: out[t] = Y[slot(t,0)] + Y[slot(t,1)]  (f32 out) ----------------
__global__ __launch_bounds__(256) void k_combine(const char* __restrict__ ws,
                                                 float* __restrict__ out) {
  int idx = blockIdx.x * 256 + threadIdx.x;          // 8 cols each
  int t = idx >> 7, c = (idx & 127) * 8;
  const int* slot_of = (const int*)(ws + WS_SLOT_OF);
  int s0 = slot_of[2 * t], s1 = slot_of[2 * t + 1];
  const unsigned short* Y = (const unsigned short*)(ws + WS_YPAIR);
  int4 ya = *(const int4*)(Y + (size_t)s0 * DM + c);
  int4 yb = *(const int4*)(Y + (size_t)s1 * DM + c);
  const unsigned short* pa = (const unsigned short*)&ya;
  const unsigned short* pb = (const unsigned short*)&yb;
  float res[8];
#pragma unroll
  for (int j = 0; j < 8; ++j) {
    res[j] = __uint_as_float((unsigned int)pa[j] << 16) +
             __uint_as_float((unsigned int)pb[j] << 16);
  }
  float4 o0 = {res[0], res[1], res[2], res[3]};
  float4 o1 = {res[4], res[5], res[6], res[7]};
  *(float4*)(out + (size_t)t * DM + c) = o0;
  *(float4*)(out + (size_t)t * DM + c + 4) = o1;
}

extern "C" void kernel_launch(void* const* d_in, const int* in_sizes, int n_in,
                              void* d_out, int out_size, void* d_ws, size_t ws_size,
                              hipStream_t stream) {
  const float* x  = (const float*)d_in[0];
  const float* rw = (const float*)d_in[1];
  const float* rb = (const float*)d_in[2];
  const float* w1 = (const float*)d_in[3];
  const float* b1 = (const float*)d_in[4];
  const float* w2 = (const float*)d_in[5];
  const float* b2 = (const float*)d_in[6];
  const float* wo = (const float*)d_in[7];
  const float* bo = (const float*)d_in[8];
  float* out = (float*)d_out;
  char* ws = (char*)d_ws;
  if (ws_size < WS_NEEDED) return;
  int big = ws_size >= WS_NEEDED_BIG;   // fast path needs ~295 MB

  hipMemsetAsync(d_ws, 0, 4096, stream);  // zero counts/psum/ntiles/cursor
  k_router<<<RT_BLOCKS, 256, 0, stream>>>(x, rw, rb, ws);
  k_scan<<<1, 64, 0, stream>>>(ws, out);
  k_fill<<<N_PAIRS / 256, 256, 0, stream>>>(ws);
  if (big) {
    k_cvt_x<<<(T_TOKENS * DM / 8) / 256, 256, 0, stream>>>(x, ws);
    k_transp<<<dim3(DH / 64, DM / 64, N_EXP), 256, 0, stream>>>(w1, ws + WS_W1T, DM, DH);
    k_transp<<<dim3(DH / 64, DM / 64, N_EXP), 256, 0, stream>>>(w2, ws + WS_W2T, DM, DH);
    k_transp<<<dim3(DM / 64, DH / 64, N_EXP), 256, 0, stream>>>(wo, ws + WS_WOT, DH, DM);
    k_gemm1_bf<<<dim3(DH / 64, MAX_TILES), 256, 0, stream>>>(b1, b2, ws);
    k_gemm2_bf<<<dim3(DM / 128, MAX_TILES), 256, 0, stream>>>(bo, ws);
  } else {
    k_gemm1<<<dim3(DH / 64, MAX_TILES), 256, 0, stream>>>(x, w1, b1, w2, b2, ws);
    k_gemm2<<<dim3(DM / 128, MAX_TILES), 256, 0, stream>>>(wo, bo, ws);
  }
  k_combine<<<(T_TOKENS * DM / 8) / 256, 256, 0, stream>>>(ws, out);
}

// Round 3
// 785.880 us; speedup vs baseline: 1.5261x; 1.0535x over previous
//
#include <hip/hip_runtime.h>
#include <hip/hip_bf16.h>
#include <stdint.h>

// SparseMOE on MI355X (gfx950). Inputs/outputs FLOAT32.
// R6: GEMMs moved to BK=32 + double-buffered LDS with the T3 "minimum 2-phase"
//     pipeline (stage next K-tile BEFORE computing current; ONE __syncthreads
//     per iter -> global latency hidden under MFMA; LDS footprint unchanged at
//     ~33 KB so occupancy stays 4 blocks/CU). BK=32 rows (64 B) are bank-even
//     for b128 column reads -> no swizzle needed. k_transp: pitch 65 + scalar
//     LDS ops (4-way read conflict -> 2-way free both sides). Router: 256 blocks.
//     Fallback to R3 f32-staging kernels if workspace < ~295 MB.

#define T_TOKENS 4096
#define DM 1024
#define DH 4096
#define N_EXP 8
#define N_PAIRS (T_TOKENS * 2)
#define MAX_TILES 96             // worst-case sum ceil(N_e/128) = 71

typedef __hip_bfloat16 bf16_t;
typedef __bf16 bf16x8 __attribute__((ext_vector_type(8)));   // MFMA A/B frag (4 VGPRs)
typedef float  f32x4  __attribute__((ext_vector_type(4)));   // MFMA C/D frag
typedef unsigned short ushort4v __attribute__((ext_vector_type(4)));

// ---- workspace layout (byte offsets) ----
#define WS_COUNTS   0        // int[8]   tokens per expert
#define WS_OFFSETS  32       // int[8]   exclusive scan
#define WS_PSUM     96       // float[8] sum of probs per expert
#define WS_NTILES   128      // int
#define WS_CURSOR   192      // int[8]   slot-assignment cursors (k_fill)
#define WS_TILE_E   256      // int[128] tile -> expert
#define WS_TILE_M0  768      // int[128] tile -> first slot
#define WS_E_OF     4096     // int[8192]   (t,k) -> expert
#define WS_W_OF     69632    // float[8192] (t,k) -> gate weight
#define WS_TOK_OF   102400   // int[8192]   slot -> token
#define WS_WT_OF    135168   // float[8192] slot -> gate weight
#define WS_SLOT_OF  167936   // int[8192]   (t,k) -> slot
#define WS_HBUF     (1u<<20)                              // bf16[8192][4096] = 64 MB
#define WS_YPAIR    (WS_HBUF + (size_t)N_PAIRS*DH*2)      // bf16[8192][1024] = 16 MB
#define WS_NEEDED   (WS_YPAIR + (size_t)N_PAIRS*DM*2)     // ~81 MB (fallback path)
// fast path: bf16 pre-converted operands
#define WS_XBF      WS_NEEDED                             // bf16[4096][1024] = 8 MB
#define WS_W1T      (WS_XBF + (size_t)T_TOKENS*DM*2)      // bf16[E][DH][DM] = 64 MB
#define WS_W2T      (WS_W1T + (size_t)N_EXP*DM*DH*2)      // bf16[E][DH][DM] = 64 MB
#define WS_WOT      (WS_W2T + (size_t)N_EXP*DM*DH*2)      // bf16[E][DM][DH] = 64 MB
#define WS_NEEDED_BIG (WS_WOT + (size_t)N_EXP*DM*DH*2)    // ~295 MB

#define PITCH 40   // LDS row pitch for fallback kernels

__device__ __forceinline__ unsigned short f2bf(float f) {
  bf16_t h = __float2bfloat16(f);   // RNE
  return *(unsigned short*)&h;
}

// async global->LDS, 16 B per lane. LDS dest = wave-uniform base + lane*16.
__device__ __forceinline__ void gload16(const void* g, void* l) {
  __builtin_amdgcn_global_load_lds(
      (const __attribute__((address_space(1))) unsigned int*)g,
      (__attribute__((address_space(3))) unsigned int*)l, 16, 0, 0);
}

// ---------------- router: 256 blocks x 256 thr; wave handles 4 tokens ----------------
#define RT_BLOCKS 256
#define RT_TPB (T_TOKENS / RT_BLOCKS)   // 16 tokens per block
#define RT_TPW (RT_TPB / 4)             // 4 tokens per wave

__global__ __launch_bounds__(256) void k_router(const float* __restrict__ x,
                                                const float* __restrict__ rw,
                                                const float* __restrict__ rb,
                                                char* __restrict__ ws) {
  __shared__ float s_psum[4][8];
  __shared__ unsigned long long s_hist[4];
  int tid = threadIdx.x, lane = tid & 63, wave = tid >> 6;
  int t0 = blockIdx.x * RT_TPB + wave * RT_TPW;
  int* e_of = (int*)(ws + WS_E_OF);
  float* w_of = (float*)(ws + WS_W_OF);

  float lpsum[8];
#pragma unroll
  for (int e = 0; e < 8; ++e) lpsum[e] = 0.f;
  unsigned long long lhist = 0ull;

  for (int tt = 0; tt < RT_TPW; ++tt) {
    int t = t0 + tt;
    float acc[8];
#pragma unroll
    for (int e = 0; e < 8; ++e) acc[e] = 0.f;
    const float* xr = x + (size_t)t * DM;
    for (int j = lane; j < DM; j += 64) {
      float xv = xr[j];
      float4 r01 = *(const float4*)(rw + j * 8);
      float4 r23 = *(const float4*)(rw + j * 8 + 4);
      acc[0] += xv * r01.x; acc[1] += xv * r01.y;
      acc[2] += xv * r01.z; acc[3] += xv * r01.w;
      acc[4] += xv * r23.x; acc[5] += xv * r23.y;
      acc[6] += xv * r23.z; acc[7] += xv * r23.w;
    }
#pragma unroll
    for (int m = 1; m < 64; m <<= 1) {
#pragma unroll
      for (int e = 0; e < 8; ++e) acc[e] += __shfl_xor(acc[e], m);
    }
    float mx = -1e30f;
#pragma unroll
    for (int e = 0; e < 8; ++e) { acc[e] += rb[e]; mx = fmaxf(mx, acc[e]); }
    float s = 0.f;
#pragma unroll
    for (int e = 0; e < 8; ++e) { acc[e] = __expf(acc[e] - mx); s += acc[e]; }
    float inv = 1.f / s;
#pragma unroll
    for (int e = 0; e < 8; ++e) { acc[e] *= inv; lpsum[e] += acc[e]; }
    int i1 = 0;
#pragma unroll
    for (int e = 1; e < 8; ++e) if (acc[e] > acc[i1]) i1 = e;
    int i2 = -1;
#pragma unroll
    for (int e = 0; e < 8; ++e) if (e != i1 && (i2 < 0 || acc[e] > acc[i2])) i2 = e;
    lhist += (1ull << (i1 * 8)) + (1ull << (i2 * 8));
    if (lane == 0) {
      e_of[2 * t] = i1; e_of[2 * t + 1] = i2;
      w_of[2 * t] = acc[i1]; w_of[2 * t + 1] = acc[i2];
    }
  }
  if (lane == 0) {
#pragma unroll
    for (int e = 0; e < 8; ++e) s_psum[wave][e] = lpsum[e];
    s_hist[wave] = lhist;
  }
  __syncthreads();
  if (tid < 8) {
    float p = s_psum[0][tid] + s_psum[1][tid] + s_psum[2][tid] + s_psum[3][tid];
    atomicAdd((float*)(ws + WS_PSUM) + tid, p);
    int c = 0;
#pragma unroll
    for (int w = 0; w < 4; ++w) c += (int)((s_hist[w] >> (tid * 8)) & 0xff);
    atomicAdd((int*)(ws + WS_COUNTS) + tid, c);
  }
}

// ---------------- scan: offsets, tile table, lb_loss ----------------
__global__ void k_scan(char* __restrict__ ws, float* __restrict__ out) {
  if (threadIdx.x == 0 && blockIdx.x == 0) {
    int* counts = (int*)(ws + WS_COUNTS);
    int* offs = (int*)(ws + WS_OFFSETS);
    int* te = (int*)(ws + WS_TILE_E);
    int* tm = (int*)(ws + WS_TILE_M0);
    int off = 0, nt = 0;
    for (int e = 0; e < 8; ++e) {
      offs[e] = off;
      for (int m0 = 0; m0 < counts[e]; m0 += 128) { te[nt] = e; tm[nt] = off + m0; ++nt; }
      off += counts[e];
    }
    *(int*)(ws + WS_NTILES) = nt;
    float* psum = (float*)(ws + WS_PSUM);
    float lb = 0.f;
    for (int e = 0; e < 8; ++e)
      lb += ((float)counts[e] / (float)T_TOKENS) * (psum[e] / (float)T_TOKENS);
    lb *= 0.01f * 8.f;
    out[(size_t)T_TOKENS * DM] = lb;
  }
}

// ---------------- fill: (t,k) -> slot via block-level ranking ----------------
__global__ __launch_bounds__(256) void k_fill(char* __restrict__ ws) {
  __shared__ int hist[8];
  __shared__ int base[8];
  int tid = threadIdx.x;
  int i = blockIdx.x * 256 + tid;
  if (tid < 8) hist[tid] = 0;
  __syncthreads();
  int e = ((const int*)(ws + WS_E_OF))[i];
  int rank = atomicAdd(&hist[e], 1);
  __syncthreads();
  if (tid < 8) base[tid] = atomicAdd((int*)(ws + WS_CURSOR) + tid, hist[tid]);
  __syncthreads();
  int slot = ((const int*)(ws + WS_OFFSETS))[e] + base[e] + rank;
  ((int*)(ws + WS_TOK_OF))[slot] = i >> 1;
  ((float*)(ws + WS_WT_OF))[slot] = ((const float*)(ws + WS_W_OF))[i];
  ((int*)(ws + WS_SLOT_OF))[i] = slot;
}

// ---------------- pre-pass: x f32 -> bf16 ----------------
__global__ __launch_bounds__(256) void k_cvt_x(const float* __restrict__ x,
                                               char* __restrict__ ws) {
  int i = blockIdx.x * 256 + threadIdx.x;          // 8 elems each
  const float* s = x + (size_t)i * 8;
  float4 a = *(const float4*)s;
  float4 b = *(const float4*)(s + 4);
  uint4 v;
  v.x = (unsigned)f2bf(a.x) | ((unsigned)f2bf(a.y) << 16);
  v.y = (unsigned)f2bf(a.z) | ((unsigned)f2bf(a.w) << 16);
  v.z = (unsigned)f2bf(b.x) | ((unsigned)f2bf(b.y) << 16);
  v.w = (unsigned)f2bf(b.z) | ((unsigned)f2bf(b.w) << 16);
  *(uint4*)(ws + WS_XBF + (size_t)i * 16) = v;
}

// ---------------- pre-pass: transpose-convert [E][K][N] f32 -> [E][N][K] bf16 ------
// 64x64 tile per block, 256 threads. Pitch 65 (odd): both LDS sides 2-way (free).
__global__ __launch_bounds__(256) void k_transp(const float* __restrict__ in,
                                                char* __restrict__ outc,
                                                int K, int N) {
  __shared__ float tile[64][65];   // odd pitch: row+16 stride not bank-aliased
  int e = blockIdx.z;
  int k0 = blockIdx.y * 64, n0 = blockIdx.x * 64;
  int tid = threadIdx.x;
  const float* src = in + ((size_t)e * K + k0) * N + n0;
  int row = tid >> 2, c4 = (tid & 3) * 16;
  float4 v[4];
#pragma unroll
  for (int j = 0; j < 4; ++j)
    v[j] = *(const float4*)(src + (size_t)row * N + c4 + j * 4);
#pragma unroll
  for (int j = 0; j < 4; ++j) {   // scalar stores: banks (row + c4 + idx)%32 -> 2-way
    tile[row][c4 + 4 * j]     = v[j].x;
    tile[row][c4 + 4 * j + 1] = v[j].y;
    tile[row][c4 + 4 * j + 2] = v[j].z;
    tile[row][c4 + 4 * j + 3] = v[j].w;
  }
  __syncthreads();
  int n = tid >> 2, kc = (tid & 3) * 16;
  unsigned int pk[8];
#pragma unroll
  for (int j = 0; j < 8; ++j) {   // reads: banks (kc+2j+n)%32 -> 2-way (was 4-way)
    unsigned int lo = f2bf(tile[kc + 2 * j][n]);
    unsigned int hi = f2bf(tile[kc + 2 * j + 1][n]);
    pk[j] = lo | (hi << 16);
  }
  char* dst = outc + ((size_t)e * K * N + (size_t)(n0 + n) * K + k0 + kc) * 2;
  uint4 v0 = {pk[0], pk[1], pk[2], pk[3]};
  uint4 v1 = {pk[4], pk[5], pk[6], pk[7]};
  *(uint4*)dst = v0;
  *(uint4*)(dst + 16) = v1;
}

// ---------------- GEMM1 (fast): H = (X@W1+b1) * silu(X@W2+b2), bf16 operands -------
// 256 thr = 4 waves (2x2), BM=128 tokens, BN=64 hidden cols (x2 matrices), BK=32.
// Double-buffered LDS, T3 minimum-2-phase: stage(t+1) issued BEFORE compute(t),
// ONE __syncthreads per iter (its vmcnt(0) drain covers the prefetch). 64-B LDS
// rows are bank-even for b128 column reads -> no swizzle needed.
#define G1_NT (DM / 32)
__global__ __launch_bounds__(256, 2) void k_gemm1_bf(const float* __restrict__ b1,
                                                     const float* __restrict__ b2,
                                                     char* __restrict__ ws) {
  __shared__ __align__(16) unsigned short As[2][128 * 32];
  __shared__ __align__(16) unsigned short Bs1[2][64 * 32];
  __shared__ __align__(16) unsigned short Bs2[2][64 * 32];
  __shared__ int tokLds[128];
  int tid = threadIdx.x;
  int tileIdx = blockIdx.y;
  if (tileIdx >= *(const int*)(ws + WS_NTILES)) return;
  int e = ((const int*)(ws + WS_TILE_E))[tileIdx];
  int m_start = ((const int*)(ws + WS_TILE_M0))[tileIdx];
  int m_end = ((const int*)(ws + WS_OFFSETS))[e] + ((const int*)(ws + WS_COUNTS))[e];
  int m_cnt = min(128, m_end - m_start);
  int n0 = blockIdx.x * 64;
  if (tid < 128) tokLds[tid] = ((const int*)(ws + WS_TOK_OF))[m_start + min(tid, m_cnt - 1)];
  __syncthreads();

  int lane = tid & 63, wave = tid >> 6;
  int wm = wave >> 1, wn = wave & 1;
  int lr = lane & 15, quad = lane >> 4;
  int rsub = lane >> 2;           // row within a 16-row staging group
  int kch = (lane & 3) * 16;      // byte chunk within the 64-B K-row

  const char* xbf = ws + WS_XBF;
  const char* w1t = ws + WS_W1T + (size_t)e * DM * DH * 2;
  const char* w2t = ws + WS_W2T + (size_t)e * DM * DH * 2;

  const char* srcA0 = xbf + (size_t)tokLds[wave * 32 + rsub] * (DM * 2) + kch;
  const char* srcA1 = xbf + (size_t)tokLds[wave * 32 + 16 + rsub] * (DM * 2) + kch;
  const char* srcB1 = w1t + (size_t)(n0 + wave * 16 + rsub) * (DM * 2) + kch;
  const char* srcB2 = w2t + (size_t)(n0 + wave * 16 + rsub) * (DM * 2) + kch;

  f32x4 acc1[4][2], acc2[4][2];
  f32x4 z = {0.f, 0.f, 0.f, 0.f};
#pragma unroll
  for (int i = 0; i < 4; ++i)
#pragma unroll
    for (int j = 0; j < 2; ++j) { acc1[i][j] = z; acc2[i][j] = z; }

  // prologue: stage K-tile 0 into buffer 0
  gload16(srcA0, &As[0][(wave * 32) * 32]);
  gload16(srcA1, &As[0][(wave * 32 + 16) * 32]);
  gload16(srcB1, &Bs1[0][(wave * 16) * 32]);
  gload16(srcB2, &Bs2[0][(wave * 16) * 32]);
  __syncthreads();

  int p = 0;
  for (int kt = 0; kt < G1_NT; ++kt) {
    if (kt + 1 < G1_NT) {        // issue next-tile loads FIRST (latency hides under MFMA)
      int kb = (kt + 1) * 64;
      gload16(srcA0 + kb, &As[p ^ 1][(wave * 32) * 32]);
      gload16(srcA1 + kb, &As[p ^ 1][(wave * 32 + 16) * 32]);
      gload16(srcB1 + kb, &Bs1[p ^ 1][(wave * 16) * 32]);
      gload16(srcB2 + kb, &Bs2[p ^ 1][(wave * 16) * 32]);
    }
    bf16x8 a[4], f1[2], f2v[2];
#pragma unroll
    for (int mt = 0; mt < 4; ++mt)
      a[mt] = *(const bf16x8*)&As[p][(wm * 64 + mt * 16 + lr) * 32 + quad * 8];
#pragma unroll
    for (int nt = 0; nt < 2; ++nt) {
      f1[nt]  = *(const bf16x8*)&Bs1[p][(wn * 32 + nt * 16 + lr) * 32 + quad * 8];
      f2v[nt] = *(const bf16x8*)&Bs2[p][(wn * 32 + nt * 16 + lr) * 32 + quad * 8];
    }
#pragma unroll
    for (int mt = 0; mt < 4; ++mt)
#pragma unroll
      for (int nt = 0; nt < 2; ++nt) {
        acc1[mt][nt] = __builtin_amdgcn_mfma_f32_16x16x32_bf16(a[mt], f1[nt],  acc1[mt][nt], 0, 0, 0);
        acc2[mt][nt] = __builtin_amdgcn_mfma_f32_16x16x32_bf16(a[mt], f2v[nt], acc2[mt][nt], 0, 0, 0);
      }
    __syncthreads();   // drains prefetch (vmcnt 0) + guards buffer reuse
    p ^= 1;
  }
  // epilogue: h = (t1+b1) * silu(t2+b2)  -> Hbuf bf16
  bf16_t* Hbuf = (bf16_t*)(ws + WS_HBUF);
#pragma unroll
  for (int mt = 0; mt < 4; ++mt) {
    int growb = wm * 64 + mt * 16 + quad * 4;   // C/D: row=(lane>>4)*4+reg, col=lane&15
#pragma unroll
    for (int nt = 0; nt < 2; ++nt) {
      int col = n0 + wn * 32 + nt * 16 + lr;
      float b1v = b1[e * DH + col];
      float b2v = b2[e * DH + col];
#pragma unroll
      for (int r = 0; r < 4; ++r) {
        int grow = growb + r;
        if (grow < m_cnt) {
          float v1 = acc1[mt][nt][r] + b1v;
          float v2 = acc2[mt][nt][r] + b2v;
          float hh = v1 * (v2 / (1.f + __expf(-v2)));
          Hbuf[(size_t)(m_start + grow) * DH + col] = __float2bfloat16(hh);
        }
      }
    }
  }
}

// ---------------- GEMM2 (fast): Y = wt * (H@wo + bo), bf16 operands ----------------
// 256 thr = 4 waves (2x2), BM=128 slots, BN=128 model cols, BK=32, K=4096.
// Same 2-phase double-buffer pipeline as GEMM1.
#define G2_NT (DH / 32)
__global__ __launch_bounds__(256, 2) void k_gemm2_bf(const float* __restrict__ bo,
                                                     char* __restrict__ ws) {
  __shared__ __align__(16) unsigned short As[2][128 * 32];
  __shared__ __align__(16) unsigned short Bs[2][128 * 32];
  int tid = threadIdx.x;
  int tileIdx = blockIdx.y;
  if (tileIdx >= *(const int*)(ws + WS_NTILES)) return;
  int e = ((const int*)(ws + WS_TILE_E))[tileIdx];
  int m_start = ((const int*)(ws + WS_TILE_M0))[tileIdx];
  int m_end = ((const int*)(ws + WS_OFFSETS))[e] + ((const int*)(ws + WS_COUNTS))[e];
  int m_cnt = min(128, m_end - m_start);
  int n0 = blockIdx.x * 128;

  int lane = tid & 63, wave = tid >> 6;
  int wm = wave >> 1, wn = wave & 1;
  int lr = lane & 15, quad = lane >> 4;
  int rsub = lane >> 2;
  int kch = (lane & 3) * 16;

  const char* hb = ws + WS_HBUF;
  const char* wot = ws + WS_WOT + (size_t)e * DM * DH * 2;

  int ra0 = wave * 32 + rsub, ra1 = wave * 32 + 16 + rsub;   // rows in [0,128)
  const char* srcA0 = hb + (size_t)(m_start + min(ra0, m_cnt - 1)) * (DH * 2) + kch;
  const char* srcA1 = hb + (size_t)(m_start + min(ra1, m_cnt - 1)) * (DH * 2) + kch;
  const char* srcB0 = wot + (size_t)(n0 + ra0) * (DH * 2) + kch;
  const char* srcB1 = wot + (size_t)(n0 + ra1) * (DH * 2) + kch;

  f32x4 acc[4][4];
  f32x4 z = {0.f, 0.f, 0.f, 0.f};
#pragma unroll
  for (int i = 0; i < 4; ++i)
#pragma unroll
    for (int j = 0; j < 4; ++j) acc[i][j] = z;

  // prologue
  gload16(srcA0, &As[0][(wave * 32) * 32]);
  gload16(srcA1, &As[0][(wave * 32 + 16) * 32]);
  gload16(srcB0, &Bs[0][(wave * 32) * 32]);
  gload16(srcB1, &Bs[0][(wave * 32 + 16) * 32]);
  __syncthreads();

  int p = 0;
  for (int kt = 0; kt < G2_NT; ++kt) {
    if (kt + 1 < G2_NT) {
      int kb = (kt + 1) * 64;
      gload16(srcA0 + kb, &As[p ^ 1][(wave * 32) * 32]);
      gload16(srcA1 + kb, &As[p ^ 1][(wave * 32 + 16) * 32]);
      gload16(srcB0 + kb, &Bs[p ^ 1][(wave * 32) * 32]);
      gload16(srcB1 + kb, &Bs[p ^ 1][(wave * 32 + 16) * 32]);
    }
    bf16x8 a[4], b[4];
#pragma unroll
    for (int mt = 0; mt < 4; ++mt)
      a[mt] = *(const bf16x8*)&As[p][(wm * 64 + mt * 16 + lr) * 32 + quad * 8];
#pragma unroll
    for (int nt = 0; nt < 4; ++nt)
      b[nt] = *(const bf16x8*)&Bs[p][(wn * 64 + nt * 16 + lr) * 32 + quad * 8];
#pragma unroll
    for (int mt = 0; mt < 4; ++mt)
#pragma unroll
      for (int nt = 0; nt < 4; ++nt)
        acc[mt][nt] = __builtin_amdgcn_mfma_f32_16x16x32_bf16(a[mt], b[nt], acc[mt][nt], 0, 0, 0);
    __syncthreads();
    p ^= 1;
  }
  bf16_t* Ypair = (bf16_t*)(ws + WS_YPAIR);
  const float* wts = (const float*)(ws + WS_WT_OF);
#pragma unroll
  for (int mt = 0; mt < 4; ++mt) {
    int growb = wm * 64 + mt * 16 + quad * 4;
#pragma unroll
    for (int nt = 0; nt < 4; ++nt) {
      int col = n0 + wn * 64 + nt * 16 + lr;
      float bov = bo[e * DM + col];
#pragma unroll
      for (int r = 0; r < 4; ++r) {
        int grow = growb + r;
        if (grow < m_cnt) {
          int slot = m_start + grow;
          Ypair[(size_t)slot * DM + col] = __float2bfloat16((acc[mt][nt][r] + bov) * wts[slot]);
        }
      }
    }
  }
}

// ================= fallback (R3) GEMMs: f32 operands, reg-stage + cvt =================
__global__ __launch_bounds__(256, 2) void k_gemm1(const float* __restrict__ x,
                                                  const float* __restrict__ w1,
                                                  const float* __restrict__ b1,
                                                  const float* __restrict__ w2,
                                                  const float* __restrict__ b2,
                                                  char* __restrict__ ws) {
  __shared__ __align__(16) unsigned short As[128 * PITCH];
  __shared__ __align__(16) unsigned short Bs1[64 * PITCH];
  __shared__ __align__(16) unsigned short Bs2[64 * PITCH];
  __shared__ int tokLds[128];
  int tid = threadIdx.x;
  int tileIdx = blockIdx.y;
  if (tileIdx >= *(const int*)(ws + WS_NTILES)) return;
  int e = ((const int*)(ws + WS_TILE_E))[tileIdx];
  int m_start = ((const int*)(ws + WS_TILE_M0))[tileIdx];
  int m_end = ((const int*)(ws + WS_OFFSETS))[e] + ((const int*)(ws + WS_COUNTS))[e];
  int m_cnt = min(128, m_end - m_start);
  int n0 = blockIdx.x * 64;
  if (tid < 128) tokLds[tid] = ((const int*)(ws + WS_TOK_OF))[m_start + min(tid, m_cnt - 1)];
  __syncthreads();

  f32x4 acc1[4][2], acc2[4][2];
  f32x4 z = {0.f, 0.f, 0.f, 0.f};
#pragma unroll
  for (int i = 0; i < 4; ++i)
#pragma unroll
    for (int j = 0; j < 2; ++j) { acc1[i][j] = z; acc2[i][j] = z; }

  int lane = tid & 63, wave = tid >> 6;
  int wm = wave >> 1, wn = wave & 1;
  int lr = lane & 15, quad = lane >> 4;
  int q = tid & 127, mat = tid >> 7;
  int pk = (q & 15) * 2, pn = (q >> 4) * 8;
  const float* Wm = mat ? w2 : w1;
  unsigned short* BsM = mat ? Bs2 : Bs1;
  const float* bBase = Wm + ((size_t)e * DM + pk) * DH + n0 + pn;

  int aRow[4], aKc[4];
  const float* aPtr[4];
#pragma unroll
  for (int h = 0; h < 4; ++h) {
    int c = tid + h * 256;
    aRow[h] = c >> 3; aKc[h] = (c & 7) * 4;
    aPtr[h] = x + (size_t)tokLds[aRow[h]] * DM + aKc[h];
  }

  float4 aR[4], bR[4];
#define G1_LOAD(k0)                                                  \
  {                                                                  \
    _Pragma("unroll")                                                \
    for (int h = 0; h < 4; ++h) aR[h] = *(const float4*)(aPtr[h] + (k0)); \
    const float* src = bBase + (size_t)(k0) * DH;                    \
    bR[0] = *(const float4*)src;                                     \
    bR[1] = *(const float4*)(src + 4);                               \
    bR[2] = *(const float4*)(src + DH);                              \
    bR[3] = *(const float4*)(src + DH + 4);                          \
  }

  G1_LOAD(0);
  for (int kt = 0; kt < DM / 32; ++kt) {
    __syncthreads();
#pragma unroll
    for (int h = 0; h < 4; ++h) {
      ushort4v wv = { f2bf(aR[h].x), f2bf(aR[h].y), f2bf(aR[h].z), f2bf(aR[h].w) };
      *(ushort4v*)&As[aRow[h] * PITCH + aKc[h]] = wv;
    }
    {
      float av[8] = {bR[0].x, bR[0].y, bR[0].z, bR[0].w, bR[1].x, bR[1].y, bR[1].z, bR[1].w};
      float bv[8] = {bR[2].x, bR[2].y, bR[2].z, bR[2].w, bR[3].x, bR[3].y, bR[3].z, bR[3].w};
#pragma unroll
      for (int j = 0; j < 8; ++j) {
        unsigned int wv = (unsigned int)f2bf(av[j]) | ((unsigned int)f2bf(bv[j]) << 16);
        *(unsigned int*)&BsM[(pn + j) * PITCH + pk] = wv;
      }
    }
    __syncthreads();
    if (kt + 1 < DM / 32) G1_LOAD((kt + 1) * 32);
    bf16x8 a[4], f1[2], f2v[2];
#pragma unroll
    for (int mt = 0; mt < 4; ++mt)
      a[mt] = *(const bf16x8*)&As[(wm * 64 + mt * 16 + lr) * PITCH + quad * 8];
#pragma unroll
    for (int nt = 0; nt < 2; ++nt) {
      f1[nt]  = *(const bf16x8*)&Bs1[(wn * 32 + nt * 16 + lr) * PITCH + quad * 8];
      f2v[nt] = *(const bf16x8*)&Bs2[(wn * 32 + nt * 16 + lr) * PITCH + quad * 8];
    }
#pragma unroll
    for (int mt = 0; mt < 4; ++mt)
#pragma unroll
      for (int nt = 0; nt < 2; ++nt) {
        acc1[mt][nt] = __builtin_amdgcn_mfma_f32_16x16x32_bf16(a[mt], f1[nt],  acc1[mt][nt], 0, 0, 0);
        acc2[mt][nt] = __builtin_amdgcn_mfma_f32_16x16x32_bf16(a[mt], f2v[nt], acc2[mt][nt], 0, 0, 0);
      }
  }
  bf16_t* Hbuf = (bf16_t*)(ws + WS_HBUF);
#pragma unroll
  for (int mt = 0; mt < 4; ++mt) {
    int growb = wm * 64 + mt * 16 + quad * 4;
#pragma unroll
    for (int nt = 0; nt < 2; ++nt) {
      int col = n0 + wn * 32 + nt * 16 + lr;
      float b1v = b1[e * DH + col];
      float b2v = b2[e * DH + col];
#pragma unroll
      for (int r = 0; r < 4; ++r) {
        int grow = growb + r;
        if (grow < m_cnt) {
          float v1 = acc1[mt][nt][r] + b1v;
          float v2 = acc2[mt][nt][r] + b2v;
          float hh = v1 * (v2 / (1.f + __expf(-v2)));
          Hbuf[(size_t)(m_start + grow) * DH + col] = __float2bfloat16(hh);
        }
      }
    }
  }
}

__global__ __launch_bounds__(256, 2) void k_gemm2(const float* __restrict__ wo,
                                                  const float* __restrict__ bo,
                                                  char* __restrict__ ws) {
  __shared__ __align__(16) unsigned short As[128 * PITCH];
  __shared__ __align__(16) unsigned short Bs[128 * PITCH];
  int tid = threadIdx.x;
  int tileIdx = blockIdx.y;
  if (tileIdx >= *(const int*)(ws + WS_NTILES)) return;
  int e = ((const int*)(ws + WS_TILE_E))[tileIdx];
  int m_start = ((const int*)(ws + WS_TILE_M0))[tileIdx];
  int m_end = ((const int*)(ws + WS_OFFSETS))[e] + ((const int*)(ws + WS_COUNTS))[e];
  int m_cnt = min(128, m_end - m_start);
  int n0 = blockIdx.x * 128;
  const bf16_t* Hbuf = (const bf16_t*)(ws + WS_HBUF);

  f32x4 acc[4][4];
  f32x4 z = {0.f, 0.f, 0.f, 0.f};
#pragma unroll
  for (int i = 0; i < 4; ++i)
#pragma unroll
    for (int j = 0; j < 4; ++j) acc[i][j] = z;

  int lane = tid & 63, wave = tid >> 6;
  int wm = wave >> 1, wn = wave & 1;
  int lr = lane & 15, quad = lane >> 4;
  int pk = (tid & 15) * 2, pn = (tid >> 4) * 8;
  const float* bBase = wo + ((size_t)e * DH + pk) * DM + n0 + pn;

  int aRow[2], aKc[2];
  const bf16_t* aPtr[2];
#pragma unroll
  for (int h = 0; h < 2; ++h) {
    int c = tid + h * 256;
    aRow[h] = c >> 2; aKc[h] = (c & 3) * 8;
    int hrow = m_start + min(aRow[h], m_cnt - 1);
    aPtr[h] = Hbuf + (size_t)hrow * DH + aKc[h];
  }

  int4 aR[2]; float4 bR[4];
#define G2_LOAD(k0)                                                  \
  {                                                                  \
    _Pragma("unroll")                                                \
    for (int h = 0; h < 2; ++h) aR[h] = *(const int4*)(aPtr[h] + (k0)); \
    const float* src = bBase + (size_t)(k0) * DM;                    \
    bR[0] = *(const float4*)src;                                     \
    bR[1] = *(const float4*)(src + 4);                               \
    bR[2] = *(const float4*)(src + DM);                              \
    bR[3] = *(const float4*)(src + DM + 4);                          \
  }

  G2_LOAD(0);
  for (int kt = 0; kt < DH / 32; ++kt) {
    __syncthreads();
#pragma unroll
    for (int h = 0; h < 2; ++h)
      *(int4*)&As[aRow[h] * PITCH + aKc[h]] = aR[h];
    {
      float av[8] = {bR[0].x, bR[0].y, bR[0].z, bR[0].w, bR[1].x, bR[1].y, bR[1].z, bR[1].w};
      float bv[8] = {bR[2].x, bR[2].y, bR[2].z, bR[2].w, bR[3].x, bR[3].y, bR[3].z, bR[3].w};
#pragma unroll
      for (int j = 0; j < 8; ++j) {
        unsigned int wv = (unsigned int)f2bf(av[j]) | ((unsigned int)f2bf(bv[j]) << 16);
        *(unsigned int*)&Bs[(pn + j) * PITCH + pk] = wv;
      }
    }
    __syncthreads();
    if (kt + 1 < DH / 32) G2_LOAD((kt + 1) * 32);
    bf16x8 a[4], b[4];
#pragma unroll
    for (int mt = 0; mt < 4; ++mt)
      a[mt] = *(const bf16x8*)&As[(wm * 64 + mt * 16 + lr) * PITCH + quad * 8];
#pragma unroll
    for (int nt = 0; nt < 4; ++nt)
      b[nt] = *(const bf16x8*)&Bs[(wn * 64 + nt * 16 + lr) * PITCH + quad * 8];
#pragma unroll
    for (int mt = 0; mt < 4; ++mt)
#pragma unroll
      for (int nt = 0; nt < 4; ++nt)
        acc[mt][nt] = __builtin_amdgcn_mfma_f32_16x16x32_bf16(a[mt], b[nt], acc[mt][nt], 0, 0, 0);
  }
  bf16_t* Ypair = (bf16_t*)(ws + WS_YPAIR);
  const float* wts = (const float*)(ws + WS_WT_OF);
#pragma unroll
  for (int mt = 0; mt < 4; ++mt) {
    int growb = wm * 64 + mt * 16 + quad * 4;
#pragma unroll
    for (int nt = 0; nt < 4; ++nt) {
      int col = n0 + wn * 64 + nt * 16 + lr;
      float bov = bo[e * DM + col];
#pragma unroll
      for (int r = 0; r < 4; ++r) {
        int grow = growb + r;
        if (grow < m_cnt) {
          int slot = m_start + grow;
          Ypair[(size_t)slot * DM + col] = __float2bfloat16((acc[mt][nt][r] + bov) * wts[slot]);
        }
      }
    }
  }
}

// ---------------- combine: out[t] = Y[slot(t,0)] + Y[slot(t,1)]  (f32 out) ----------------
__global__ __launch_bounds__(256) void k_combine(const char* __restrict__ ws,
                                                 float* __restrict__ out) {
  int idx = blockIdx.x * 256 + threadIdx.x;          // 8 cols each
  int t = idx >> 7, c = (idx & 127) * 8;
  const int* slot_of = (const int*)(ws + WS_SLOT_OF);
  int s0 = slot_of[2 * t], s1 = slot_of[2 * t + 1];
  const unsigned short* Y = (const unsigned short*)(ws + WS_YPAIR);
  int4 ya = *(const int4*)(Y + (size_t)s0 * DM + c);
  int4 yb = *(const int4*)(Y + (size_t)s1 * DM + c);
  const unsigned short* pa = (const unsigned short*)&ya;
  const unsigned short* pb = (const unsigned short*)&yb;
  float res[8];
#pragma unroll
  for (int j = 0; j < 8; ++j) {
    res[j] = __uint_as_float((unsigned int)pa[j] << 16) +
             __uint_as_float((unsigned int)pb[j] << 16);
  }
  float4 o0 = {res[0], res[1], res[2], res[3]};
  float4 o1 = {res[4], res[5], res[6], res[7]};
  *(float4*)(out + (size_t)t * DM + c) = o0;
  *(float4*)(out + (size_t)t * DM + c + 4) = o1;
}

extern "C" void kernel_launch(void* const* d_in, const int* in_sizes, int n_in,
                              void* d_out, int out_size, void* d_ws, size_t ws_size,
                              hipStream_t stream) {
  const float* x  = (const float*)d_in[0];
  const float* rw = (const float*)d_in[1];
  const float* rb = (const float*)d_in[2];
  const float* w1 = (const float*)d_in[3];
  const float* b1 = (const float*)d_in[4];
  const float* w2 = (const float*)d_in[5];
  const float* b2 = (const float*)d_in[6];
  const float* wo = (const float*)d_in[7];
  const float* bo = (const float*)d_in[8];
  float* out = (float*)d_out;
  char* ws = (char*)d_ws;
  if (ws_size < WS_NEEDED) return;
  int big = ws_size >= WS_NEEDED_BIG;   // fast path needs ~295 MB

  hipMemsetAsync(d_ws, 0, 4096, stream);  // zero counts/psum/ntiles/cursor
  k_router<<<RT_BLOCKS, 256, 0, stream>>>(x, rw, rb, ws);
  k_scan<<<1, 64, 0, stream>>>(ws, out);
  k_fill<<<N_PAIRS / 256, 256, 0, stream>>>(ws);
  if (big) {
    k_cvt_x<<<(T_TOKENS * DM / 8) / 256, 256, 0, stream>>>(x, ws);
    k_transp<<<dim3(DH / 64, DM / 64, N_EXP), 256, 0, stream>>>(w1, ws + WS_W1T, DM, DH);
    k_transp<<<dim3(DH / 64, DM / 64, N_EXP), 256, 0, stream>>>(w2, ws + WS_W2T, DM, DH);
    k_transp<<<dim3(DM / 64, DH / 64, N_EXP), 256, 0, stream>>>(wo, ws + WS_WOT, DH, DM);
    k_gemm1_bf<<<dim3(DH / 64, MAX_TILES), 256, 0, stream>>>(b1, b2, ws);
    k_gemm2_bf<<<dim3(DM / 128, MAX_TILES), 256, 0, stream>>>(bo, ws);
  } else {
    k_gemm1<<<dim3(DH / 64, MAX_TILES), 256, 0, stream>>>(x, w1, b1, w2, b2, ws);
    k_gemm2<<<dim3(DM / 128, MAX_TILES), 256, 0, stream>>>(wo, bo, ws);
  }
  k_combine<<<(T_TOKENS * DM / 8) / 256, 256, 0, stream>>>(ws, out);
}

// Round 4
// 785.826 us; speedup vs baseline: 1.5262x; 1.0001x over previous
//
#include <hip/hip_runtime.h>
#include <hip/hip_bf16.h>
#include <stdint.h>

// SparseMOE on MI355X (gfx950). Inputs/outputs FLOAT32.
// R7: R6's BK=32 double-buffered 2-phase GEMM pipeline + the missing LDS chunk
//     swizzle. R6 regressed (bank conflicts 0 -> 1.78e7, MfmaUtil 37->28%):
//     64-B rows give chunk id (4*row+quad)%8 = only 2 values per 16-lane group
//     = 8-way conflict. Fix: row-dependent chunk XOR f(row)=(row>>1)&3 applied
//     on the global SOURCE (store side, linear global_load_lds dest) and on the
//     ds_read chunk (read side) -> full 8-chunk coverage, 2-way (free).
//     Everything else identical to R6 (transp pitch-65, router 256 blocks).
//     Fallback to R3 f32-staging kernels if workspace < ~295 MB.

#define T_TOKENS 4096
#define DM 1024
#define DH 4096
#define N_EXP 8
#define N_PAIRS (T_TOKENS * 2)
#define MAX_TILES 96             // worst-case sum ceil(N_e/128) = 71

typedef __hip_bfloat16 bf16_t;
typedef __bf16 bf16x8 __attribute__((ext_vector_type(8)));   // MFMA A/B frag (4 VGPRs)
typedef float  f32x4  __attribute__((ext_vector_type(4)));   // MFMA C/D frag
typedef unsigned short ushort4v __attribute__((ext_vector_type(4)));

// ---- workspace layout (byte offsets) ----
#define WS_COUNTS   0        // int[8]   tokens per expert
#define WS_OFFSETS  32       // int[8]   exclusive scan
#define WS_PSUM     96       // float[8] sum of probs per expert
#define WS_NTILES   128      // int
#define WS_CURSOR   192      // int[8]   slot-assignment cursors (k_fill)
#define WS_TILE_E   256      // int[128] tile -> expert
#define WS_TILE_M0  768      // int[128] tile -> first slot
#define WS_E_OF     4096     // int[8192]   (t,k) -> expert
#define WS_W_OF     69632    // float[8192] (t,k) -> gate weight
#define WS_TOK_OF   102400   // int[8192]   slot -> token
#define WS_WT_OF    135168   // float[8192] slot -> gate weight
#define WS_SLOT_OF  167936   // int[8192]   (t,k) -> slot
#define WS_HBUF     (1u<<20)                              // bf16[8192][4096] = 64 MB
#define WS_YPAIR    (WS_HBUF + (size_t)N_PAIRS*DH*2)      // bf16[8192][1024] = 16 MB
#define WS_NEEDED   (WS_YPAIR + (size_t)N_PAIRS*DM*2)     // ~81 MB (fallback path)
// fast path: bf16 pre-converted operands
#define WS_XBF      WS_NEEDED                             // bf16[4096][1024] = 8 MB
#define WS_W1T      (WS_XBF + (size_t)T_TOKENS*DM*2)      // bf16[E][DH][DM] = 64 MB
#define WS_W2T      (WS_W1T + (size_t)N_EXP*DM*DH*2)      // bf16[E][DH][DM] = 64 MB
#define WS_WOT      (WS_W2T + (size_t)N_EXP*DM*DH*2)      // bf16[E][DM][DH] = 64 MB
#define WS_NEEDED_BIG (WS_WOT + (size_t)N_EXP*DM*DH*2)    // ~295 MB

#define PITCH 40   // LDS row pitch for fallback kernels

__device__ __forceinline__ unsigned short f2bf(float f) {
  bf16_t h = __float2bfloat16(f);   // RNE
  return *(unsigned short*)&h;
}

// async global->LDS, 16 B per lane. LDS dest = wave-uniform base + lane*16.
__device__ __forceinline__ void gload16(const void* g, void* l) {
  __builtin_amdgcn_global_load_lds(
      (const __attribute__((address_space(1))) unsigned int*)g,
      (__attribute__((address_space(3))) unsigned int*)l, 16, 0, 0);
}

// ---------------- router: 256 blocks x 256 thr; wave handles 4 tokens ----------------
#define RT_BLOCKS 256
#define RT_TPB (T_TOKENS / RT_BLOCKS)   // 16 tokens per block
#define RT_TPW (RT_TPB / 4)             // 4 tokens per wave

__global__ __launch_bounds__(256) void k_router(const float* __restrict__ x,
                                                const float* __restrict__ rw,
                                                const float* __restrict__ rb,
                                                char* __restrict__ ws) {
  __shared__ float s_psum[4][8];
  __shared__ unsigned long long s_hist[4];
  int tid = threadIdx.x, lane = tid & 63, wave = tid >> 6;
  int t0 = blockIdx.x * RT_TPB + wave * RT_TPW;
  int* e_of = (int*)(ws + WS_E_OF);
  float* w_of = (float*)(ws + WS_W_OF);

  float lpsum[8];
#pragma unroll
  for (int e = 0; e < 8; ++e) lpsum[e] = 0.f;
  unsigned long long lhist = 0ull;

  for (int tt = 0; tt < RT_TPW; ++tt) {
    int t = t0 + tt;
    float acc[8];
#pragma unroll
    for (int e = 0; e < 8; ++e) acc[e] = 0.f;
    const float* xr = x + (size_t)t * DM;
    for (int j = lane; j < DM; j += 64) {
      float xv = xr[j];
      float4 r01 = *(const float4*)(rw + j * 8);
      float4 r23 = *(const float4*)(rw + j * 8 + 4);
      acc[0] += xv * r01.x; acc[1] += xv * r01.y;
      acc[2] += xv * r01.z; acc[3] += xv * r01.w;
      acc[4] += xv * r23.x; acc[5] += xv * r23.y;
      acc[6] += xv * r23.z; acc[7] += xv * r23.w;
    }
#pragma unroll
    for (int m = 1; m < 64; m <<= 1) {
#pragma unroll
      for (int e = 0; e < 8; ++e) acc[e] += __shfl_xor(acc[e], m);
    }
    float mx = -1e30f;
#pragma unroll
    for (int e = 0; e < 8; ++e) { acc[e] += rb[e]; mx = fmaxf(mx, acc[e]); }
    float s = 0.f;
#pragma unroll
    for (int e = 0; e < 8; ++e) { acc[e] = __expf(acc[e] - mx); s += acc[e]; }
    float inv = 1.f / s;
#pragma unroll
    for (int e = 0; e < 8; ++e) { acc[e] *= inv; lpsum[e] += acc[e]; }
    int i1 = 0;
#pragma unroll
    for (int e = 1; e < 8; ++e) if (acc[e] > acc[i1]) i1 = e;
    int i2 = -1;
#pragma unroll
    for (int e = 0; e < 8; ++e) if (e != i1 && (i2 < 0 || acc[e] > acc[i2])) i2 = e;
    lhist += (1ull << (i1 * 8)) + (1ull << (i2 * 8));
    if (lane == 0) {
      e_of[2 * t] = i1; e_of[2 * t + 1] = i2;
      w_of[2 * t] = acc[i1]; w_of[2 * t + 1] = acc[i2];
    }
  }
  if (lane == 0) {
#pragma unroll
    for (int e = 0; e < 8; ++e) s_psum[wave][e] = lpsum[e];
    s_hist[wave] = lhist;
  }
  __syncthreads();
  if (tid < 8) {
    float p = s_psum[0][tid] + s_psum[1][tid] + s_psum[2][tid] + s_psum[3][tid];
    atomicAdd((float*)(ws + WS_PSUM) + tid, p);
    int c = 0;
#pragma unroll
    for (int w = 0; w < 4; ++w) c += (int)((s_hist[w] >> (tid * 8)) & 0xff);
    atomicAdd((int*)(ws + WS_COUNTS) + tid, c);
  }
}

// ---------------- scan: offsets, tile table, lb_loss ----------------
__global__ void k_scan(char* __restrict__ ws, float* __restrict__ out) {
  if (threadIdx.x == 0 && blockIdx.x == 0) {
    int* counts = (int*)(ws + WS_COUNTS);
    int* offs = (int*)(ws + WS_OFFSETS);
    int* te = (int*)(ws + WS_TILE_E);
    int* tm = (int*)(ws + WS_TILE_M0);
    int off = 0, nt = 0;
    for (int e = 0; e < 8; ++e) {
      offs[e] = off;
      for (int m0 = 0; m0 < counts[e]; m0 += 128) { te[nt] = e; tm[nt] = off + m0; ++nt; }
      off += counts[e];
    }
    *(int*)(ws + WS_NTILES) = nt;
    float* psum = (float*)(ws + WS_PSUM);
    float lb = 0.f;
    for (int e = 0; e < 8; ++e)
      lb += ((float)counts[e] / (float)T_TOKENS) * (psum[e] / (float)T_TOKENS);
    lb *= 0.01f * 8.f;
    out[(size_t)T_TOKENS * DM] = lb;
  }
}

// ---------------- fill: (t,k) -> slot via block-level ranking ----------------
__global__ __launch_bounds__(256) void k_fill(char* __restrict__ ws) {
  __shared__ int hist[8];
  __shared__ int base[8];
  int tid = threadIdx.x;
  int i = blockIdx.x * 256 + tid;
  if (tid < 8) hist[tid] = 0;
  __syncthreads();
  int e = ((const int*)(ws + WS_E_OF))[i];
  int rank = atomicAdd(&hist[e], 1);
  __syncthreads();
  if (tid < 8) base[tid] = atomicAdd((int*)(ws + WS_CURSOR) + tid, hist[tid]);
  __syncthreads();
  int slot = ((const int*)(ws + WS_OFFSETS))[e] + base[e] + rank;
  ((int*)(ws + WS_TOK_OF))[slot] = i >> 1;
  ((float*)(ws + WS_WT_OF))[slot] = ((const float*)(ws + WS_W_OF))[i];
  ((int*)(ws + WS_SLOT_OF))[i] = slot;
}

// ---------------- pre-pass: x f32 -> bf16 ----------------
__global__ __launch_bounds__(256) void k_cvt_x(const float* __restrict__ x,
                                               char* __restrict__ ws) {
  int i = blockIdx.x * 256 + threadIdx.x;          // 8 elems each
  const float* s = x + (size_t)i * 8;
  float4 a = *(const float4*)s;
  float4 b = *(const float4*)(s + 4);
  uint4 v;
  v.x = (unsigned)f2bf(a.x) | ((unsigned)f2bf(a.y) << 16);
  v.y = (unsigned)f2bf(a.z) | ((unsigned)f2bf(a.w) << 16);
  v.z = (unsigned)f2bf(b.x) | ((unsigned)f2bf(b.y) << 16);
  v.w = (unsigned)f2bf(b.z) | ((unsigned)f2bf(b.w) << 16);
  *(uint4*)(ws + WS_XBF + (size_t)i * 16) = v;
}

// ---------------- pre-pass: transpose-convert [E][K][N] f32 -> [E][N][K] bf16 ------
// 64x64 tile per block, 256 threads. Pitch 65 (odd): both LDS sides 2-way (free).
__global__ __launch_bounds__(256) void k_transp(const float* __restrict__ in,
                                                char* __restrict__ outc,
                                                int K, int N) {
  __shared__ float tile[64][65];   // odd pitch: row+16 stride not bank-aliased
  int e = blockIdx.z;
  int k0 = blockIdx.y * 64, n0 = blockIdx.x * 64;
  int tid = threadIdx.x;
  const float* src = in + ((size_t)e * K + k0) * N + n0;
  int row = tid >> 2, c4 = (tid & 3) * 16;
  float4 v[4];
#pragma unroll
  for (int j = 0; j < 4; ++j)
    v[j] = *(const float4*)(src + (size_t)row * N + c4 + j * 4);
#pragma unroll
  for (int j = 0; j < 4; ++j) {   // scalar stores: banks (row + c4 + idx)%32 -> 2-way
    tile[row][c4 + 4 * j]     = v[j].x;
    tile[row][c4 + 4 * j + 1] = v[j].y;
    tile[row][c4 + 4 * j + 2] = v[j].z;
    tile[row][c4 + 4 * j + 3] = v[j].w;
  }
  __syncthreads();
  int n = tid >> 2, kc = (tid & 3) * 16;
  unsigned int pk[8];
#pragma unroll
  for (int j = 0; j < 8; ++j) {   // reads: banks (kc+2j+n)%32 -> 2-way (was 4-way)
    unsigned int lo = f2bf(tile[kc + 2 * j][n]);
    unsigned int hi = f2bf(tile[kc + 2 * j + 1][n]);
    pk[j] = lo | (hi << 16);
  }
  char* dst = outc + ((size_t)e * K * N + (size_t)(n0 + n) * K + k0 + kc) * 2;
  uint4 v0 = {pk[0], pk[1], pk[2], pk[3]};
  uint4 v1 = {pk[4], pk[5], pk[6], pk[7]};
  *(uint4*)dst = v0;
  *(uint4*)(dst + 16) = v1;
}

// ---------------- GEMM1 (fast): H = (X@W1+b1) * silu(X@W2+b2), bf16 operands -------
// 256 thr = 4 waves (2x2), BM=128 tokens, BN=64 hidden cols (x2 matrices), BK=32.
// Double-buffered LDS, 2-phase: stage(t+1) issued BEFORE compute(t), ONE
// __syncthreads per iter. Chunk swizzle f(row)=(row>>1)&3: store side uses
// inverse-swizzled global source (linear global_load_lds dest), read side XORs
// the 16-B chunk -> chunk id (4*row + quad^f)%8 covers all 8 -> 2-way (free).
#define G1_NT (DM / 32)
__global__ __launch_bounds__(256, 2) void k_gemm1_bf(const float* __restrict__ b1,
                                                     const float* __restrict__ b2,
                                                     char* __restrict__ ws) {
  __shared__ __align__(16) unsigned short As[2][128 * 32];
  __shared__ __align__(16) unsigned short Bs1[2][64 * 32];
  __shared__ __align__(16) unsigned short Bs2[2][64 * 32];
  __shared__ int tokLds[128];
  int tid = threadIdx.x;
  int tileIdx = blockIdx.y;
  if (tileIdx >= *(const int*)(ws + WS_NTILES)) return;
  int e = ((const int*)(ws + WS_TILE_E))[tileIdx];
  int m_start = ((const int*)(ws + WS_TILE_M0))[tileIdx];
  int m_end = ((const int*)(ws + WS_OFFSETS))[e] + ((const int*)(ws + WS_COUNTS))[e];
  int m_cnt = min(128, m_end - m_start);
  int n0 = blockIdx.x * 64;
  if (tid < 128) tokLds[tid] = ((const int*)(ws + WS_TOK_OF))[m_start + min(tid, m_cnt - 1)];
  __syncthreads();

  int lane = tid & 63, wave = tid >> 6;
  int wm = wave >> 1, wn = wave & 1;
  int lr = lane & 15, quad = lane >> 4;
  int rsub = lane >> 2;                             // staging row within 16-row group
  int kch = ((lane & 3) ^ ((rsub >> 1) & 3)) * 16;  // inverse-swizzled source chunk
  int csw = (quad ^ ((lr >> 1) & 3)) * 8;           // read-side swizzled chunk (elems)

  const char* xbf = ws + WS_XBF;
  const char* w1t = ws + WS_W1T + (size_t)e * DM * DH * 2;
  const char* w2t = ws + WS_W2T + (size_t)e * DM * DH * 2;

  const char* srcA0 = xbf + (size_t)tokLds[wave * 32 + rsub] * (DM * 2) + kch;
  const char* srcA1 = xbf + (size_t)tokLds[wave * 32 + 16 + rsub] * (DM * 2) + kch;
  const char* srcB1 = w1t + (size_t)(n0 + wave * 16 + rsub) * (DM * 2) + kch;
  const char* srcB2 = w2t + (size_t)(n0 + wave * 16 + rsub) * (DM * 2) + kch;

  f32x4 acc1[4][2], acc2[4][2];
  f32x4 z = {0.f, 0.f, 0.f, 0.f};
#pragma unroll
  for (int i = 0; i < 4; ++i)
#pragma unroll
    for (int j = 0; j < 2; ++j) { acc1[i][j] = z; acc2[i][j] = z; }

  // prologue: stage K-tile 0 into buffer 0
  gload16(srcA0, &As[0][(wave * 32) * 32]);
  gload16(srcA1, &As[0][(wave * 32 + 16) * 32]);
  gload16(srcB1, &Bs1[0][(wave * 16) * 32]);
  gload16(srcB2, &Bs2[0][(wave * 16) * 32]);
  __syncthreads();

  int p = 0;
  for (int kt = 0; kt < G1_NT; ++kt) {
    if (kt + 1 < G1_NT) {        // issue next-tile loads FIRST (latency hides under MFMA)
      int kb = (kt + 1) * 64;
      gload16(srcA0 + kb, &As[p ^ 1][(wave * 32) * 32]);
      gload16(srcA1 + kb, &As[p ^ 1][(wave * 32 + 16) * 32]);
      gload16(srcB1 + kb, &Bs1[p ^ 1][(wave * 16) * 32]);
      gload16(srcB2 + kb, &Bs2[p ^ 1][(wave * 16) * 32]);
    }
    bf16x8 a[4], f1[2], f2v[2];
#pragma unroll
    for (int mt = 0; mt < 4; ++mt)
      a[mt] = *(const bf16x8*)&As[p][(wm * 64 + mt * 16 + lr) * 32 + csw];
#pragma unroll
    for (int nt = 0; nt < 2; ++nt) {
      f1[nt]  = *(const bf16x8*)&Bs1[p][(wn * 32 + nt * 16 + lr) * 32 + csw];
      f2v[nt] = *(const bf16x8*)&Bs2[p][(wn * 32 + nt * 16 + lr) * 32 + csw];
    }
#pragma unroll
    for (int mt = 0; mt < 4; ++mt)
#pragma unroll
      for (int nt = 0; nt < 2; ++nt) {
        acc1[mt][nt] = __builtin_amdgcn_mfma_f32_16x16x32_bf16(a[mt], f1[nt],  acc1[mt][nt], 0, 0, 0);
        acc2[mt][nt] = __builtin_amdgcn_mfma_f32_16x16x32_bf16(a[mt], f2v[nt], acc2[mt][nt], 0, 0, 0);
      }
    __syncthreads();   // drains prefetch (vmcnt 0) + guards buffer reuse
    p ^= 1;
  }
  // epilogue: h = (t1+b1) * silu(t2+b2)  -> Hbuf bf16
  bf16_t* Hbuf = (bf16_t*)(ws + WS_HBUF);
#pragma unroll
  for (int mt = 0; mt < 4; ++mt) {
    int growb = wm * 64 + mt * 16 + quad * 4;   // C/D: row=(lane>>4)*4+reg, col=lane&15
#pragma unroll
    for (int nt = 0; nt < 2; ++nt) {
      int col = n0 + wn * 32 + nt * 16 + lr;
      float b1v = b1[e * DH + col];
      float b2v = b2[e * DH + col];
#pragma unroll
      for (int r = 0; r < 4; ++r) {
        int grow = growb + r;
        if (grow < m_cnt) {
          float v1 = acc1[mt][nt][r] + b1v;
          float v2 = acc2[mt][nt][r] + b2v;
          float hh = v1 * (v2 / (1.f + __expf(-v2)));
          Hbuf[(size_t)(m_start + grow) * DH + col] = __float2bfloat16(hh);
        }
      }
    }
  }
}

// ---------------- GEMM2 (fast): Y = wt * (H@wo + bo), bf16 operands ----------------
// 256 thr = 4 waves (2x2), BM=128 slots, BN=128 model cols, BK=32, K=4096.
// Same 2-phase double-buffer pipeline + chunk swizzle as GEMM1.
#define G2_NT (DH / 32)
__global__ __launch_bounds__(256, 2) void k_gemm2_bf(const float* __restrict__ bo,
                                                     char* __restrict__ ws) {
  __shared__ __align__(16) unsigned short As[2][128 * 32];
  __shared__ __align__(16) unsigned short Bs[2][128 * 32];
  int tid = threadIdx.x;
  int tileIdx = blockIdx.y;
  if (tileIdx >= *(const int*)(ws + WS_NTILES)) return;
  int e = ((const int*)(ws + WS_TILE_E))[tileIdx];
  int m_start = ((const int*)(ws + WS_TILE_M0))[tileIdx];
  int m_end = ((const int*)(ws + WS_OFFSETS))[e] + ((const int*)(ws + WS_COUNTS))[e];
  int m_cnt = min(128, m_end - m_start);
  int n0 = blockIdx.x * 128;

  int lane = tid & 63, wave = tid >> 6;
  int wm = wave >> 1, wn = wave & 1;
  int lr = lane & 15, quad = lane >> 4;
  int rsub = lane >> 2;
  int kch = ((lane & 3) ^ ((rsub >> 1) & 3)) * 16;
  int csw = (quad ^ ((lr >> 1) & 3)) * 8;

  const char* hb = ws + WS_HBUF;
  const char* wot = ws + WS_WOT + (size_t)e * DM * DH * 2;

  int ra0 = wave * 32 + rsub, ra1 = wave * 32 + 16 + rsub;   // rows in [0,128)
  const char* srcA0 = hb + (size_t)(m_start + min(ra0, m_cnt - 1)) * (DH * 2) + kch;
  const char* srcA1 = hb + (size_t)(m_start + min(ra1, m_cnt - 1)) * (DH * 2) + kch;
  const char* srcB0 = wot + (size_t)(n0 + ra0) * (DH * 2) + kch;
  const char* srcB1 = wot + (size_t)(n0 + ra1) * (DH * 2) + kch;

  f32x4 acc[4][4];
  f32x4 z = {0.f, 0.f, 0.f, 0.f};
#pragma unroll
  for (int i = 0; i < 4; ++i)
#pragma unroll
    for (int j = 0; j < 4; ++j) acc[i][j] = z;

  // prologue
  gload16(srcA0, &As[0][(wave * 32) * 32]);
  gload16(srcA1, &As[0][(wave * 32 + 16) * 32]);
  gload16(srcB0, &Bs[0][(wave * 32) * 32]);
  gload16(srcB1, &Bs[0][(wave * 32 + 16) * 32]);
  __syncthreads();

  int p = 0;
  for (int kt = 0; kt < G2_NT; ++kt) {
    if (kt + 1 < G2_NT) {
      int kb = (kt + 1) * 64;
      gload16(srcA0 + kb, &As[p ^ 1][(wave * 32) * 32]);
      gload16(srcA1 + kb, &As[p ^ 1][(wave * 32 + 16) * 32]);
      gload16(srcB0 + kb, &Bs[p ^ 1][(wave * 32) * 32]);
      gload16(srcB1 + kb, &Bs[p ^ 1][(wave * 32 + 16) * 32]);
    }
    bf16x8 a[4], b[4];
#pragma unroll
    for (int mt = 0; mt < 4; ++mt)
      a[mt] = *(const bf16x8*)&As[p][(wm * 64 + mt * 16 + lr) * 32 + csw];
#pragma unroll
    for (int nt = 0; nt < 4; ++nt)
      b[nt] = *(const bf16x8*)&Bs[p][(wn * 64 + nt * 16 + lr) * 32 + csw];
#pragma unroll
    for (int mt = 0; mt < 4; ++mt)
#pragma unroll
      for (int nt = 0; nt < 4; ++nt)
        acc[mt][nt] = __builtin_amdgcn_mfma_f32_16x16x32_bf16(a[mt], b[nt], acc[mt][nt], 0, 0, 0);
    __syncthreads();
    p ^= 1;
  }
  bf16_t* Ypair = (bf16_t*)(ws + WS_YPAIR);
  const float* wts = (const float*)(ws + WS_WT_OF);
#pragma unroll
  for (int mt = 0; mt < 4; ++mt) {
    int growb = wm * 64 + mt * 16 + quad * 4;
#pragma unroll
    for (int nt = 0; nt < 4; ++nt) {
      int col = n0 + wn * 64 + nt * 16 + lr;
      float bov = bo[e * DM + col];
#pragma unroll
      for (int r = 0; r < 4; ++r) {
        int grow = growb + r;
        if (grow < m_cnt) {
          int slot = m_start + grow;
          Ypair[(size_t)slot * DM + col] = __float2bfloat16((acc[mt][nt][r] + bov) * wts[slot]);
        }
      }
    }
  }
}

// ================= fallback (R3) GEMMs: f32 operands, reg-stage + cvt =================
__global__ __launch_bounds__(256, 2) void k_gemm1(const float* __restrict__ x,
                                                  const float* __restrict__ w1,
                                                  const float* __restrict__ b1,
                                                  const float* __restrict__ w2,
                                                  const float* __restrict__ b2,
                                                  char* __restrict__ ws) {
  __shared__ __align__(16) unsigned short As[128 * PITCH];
  __shared__ __align__(16) unsigned short Bs1[64 * PITCH];
  __shared__ __align__(16) unsigned short Bs2[64 * PITCH];
  __shared__ int tokLds[128];
  int tid = threadIdx.x;
  int tileIdx = blockIdx.y;
  if (tileIdx >= *(const int*)(ws + WS_NTILES)) return;
  int e = ((const int*)(ws + WS_TILE_E))[tileIdx];
  int m_start = ((const int*)(ws + WS_TILE_M0))[tileIdx];
  int m_end = ((const int*)(ws + WS_OFFSETS))[e] + ((const int*)(ws + WS_COUNTS))[e];
  int m_cnt = min(128, m_end - m_start);
  int n0 = blockIdx.x * 64;
  if (tid < 128) tokLds[tid] = ((const int*)(ws + WS_TOK_OF))[m_start + min(tid, m_cnt - 1)];
  __syncthreads();

  f32x4 acc1[4][2], acc2[4][2];
  f32x4 z = {0.f, 0.f, 0.f, 0.f};
#pragma unroll
  for (int i = 0; i < 4; ++i)
#pragma unroll
    for (int j = 0; j < 2; ++j) { acc1[i][j] = z; acc2[i][j] = z; }

  int lane = tid & 63, wave = tid >> 6;
  int wm = wave >> 1, wn = wave & 1;
  int lr = lane & 15, quad = lane >> 4;
  int q = tid & 127, mat = tid >> 7;
  int pk = (q & 15) * 2, pn = (q >> 4) * 8;
  const float* Wm = mat ? w2 : w1;
  unsigned short* BsM = mat ? Bs2 : Bs1;
  const float* bBase = Wm + ((size_t)e * DM + pk) * DH + n0 + pn;

  int aRow[4], aKc[4];
  const float* aPtr[4];
#pragma unroll
  for (int h = 0; h < 4; ++h) {
    int c = tid + h * 256;
    aRow[h] = c >> 3; aKc[h] = (c & 7) * 4;
    aPtr[h] = x + (size_t)tokLds[aRow[h]] * DM + aKc[h];
  }

  float4 aR[4], bR[4];
#define G1_LOAD(k0)                                                  \
  {                                                                  \
    _Pragma("unroll")                                                \
    for (int h = 0; h < 4; ++h) aR[h] = *(const float4*)(aPtr[h] + (k0)); \
    const float* src = bBase + (size_t)(k0) * DH;                    \
    bR[0] = *(const float4*)src;                                     \
    bR[1] = *(const float4*)(src + 4);                               \
    bR[2] = *(const float4*)(src + DH);                              \
    bR[3] = *(const float4*)(src + DH + 4);                          \
  }

  G1_LOAD(0);
  for (int kt = 0; kt < DM / 32; ++kt) {
    __syncthreads();
#pragma unroll
    for (int h = 0; h < 4; ++h) {
      ushort4v wv = { f2bf(aR[h].x), f2bf(aR[h].y), f2bf(aR[h].z), f2bf(aR[h].w) };
      *(ushort4v*)&As[aRow[h] * PITCH + aKc[h]] = wv;
    }
    {
      float av[8] = {bR[0].x, bR[0].y, bR[0].z, bR[0].w, bR[1].x, bR[1].y, bR[1].z, bR[1].w};
      float bv[8] = {bR[2].x, bR[2].y, bR[2].z, bR[2].w, bR[3].x, bR[3].y, bR[3].z, bR[3].w};
#pragma unroll
      for (int j = 0; j < 8; ++j) {
        unsigned int wv = (unsigned int)f2bf(av[j]) | ((unsigned int)f2bf(bv[j]) << 16);
        *(unsigned int*)&BsM[(pn + j) * PITCH + pk] = wv;
      }
    }
    __syncthreads();
    if (kt + 1 < DM / 32) G1_LOAD((kt + 1) * 32);
    bf16x8 a[4], f1[2], f2v[2];
#pragma unroll
    for (int mt = 0; mt < 4; ++mt)
      a[mt] = *(const bf16x8*)&As[(wm * 64 + mt * 16 + lr) * PITCH + quad * 8];
#pragma unroll
    for (int nt = 0; nt < 2; ++nt) {
      f1[nt]  = *(const bf16x8*)&Bs1[(wn * 32 + nt * 16 + lr) * PITCH + quad * 8];
      f2v[nt] = *(const bf16x8*)&Bs2[(wn * 32 + nt * 16 + lr) * PITCH + quad * 8];
    }
#pragma unroll
    for (int mt = 0; mt < 4; ++mt)
#pragma unroll
      for (int nt = 0; nt < 2; ++nt) {
        acc1[mt][nt] = __builtin_amdgcn_mfma_f32_16x16x32_bf16(a[mt], f1[nt],  acc1[mt][nt], 0, 0, 0);
        acc2[mt][nt] = __builtin_amdgcn_mfma_f32_16x16x32_bf16(a[mt], f2v[nt], acc2[mt][nt], 0, 0, 0);
      }
  }
  bf16_t* Hbuf = (bf16_t*)(ws + WS_HBUF);
#pragma unroll
  for (int mt = 0; mt < 4; ++mt) {
    int growb = wm * 64 + mt * 16 + quad * 4;
#pragma unroll
    for (int nt = 0; nt < 2; ++nt) {
      int col = n0 + wn * 32 + nt * 16 + lr;
      float b1v = b1[e * DH + col];
      float b2v = b2[e * DH + col];
#pragma unroll
      for (int r = 0; r < 4; ++r) {
        int grow = growb + r;
        if (grow < m_cnt) {
          float v1 = acc1[mt][nt][r] + b1v;
          float v2 = acc2[mt][nt][r] + b2v;
          float hh = v1 * (v2 / (1.f + __expf(-v2)));
          Hbuf[(size_t)(m_start + grow) * DH + col] = __float2bfloat16(hh);
        }
      }
    }
  }
}

__global__ __launch_bounds__(256, 2) void k_gemm2(const float* __restrict__ wo,
                                                  const float* __restrict__ bo,
                                                  char* __restrict__ ws) {
  __shared__ __align__(16) unsigned short As[128 * PITCH];
  __shared__ __align__(16) unsigned short Bs[128 * PITCH];
  int tid = threadIdx.x;
  int tileIdx = blockIdx.y;
  if (tileIdx >= *(const int*)(ws + WS_NTILES)) return;
  int e = ((const int*)(ws + WS_TILE_E))[tileIdx];
  int m_start = ((const int*)(ws + WS_TILE_M0))[tileIdx];
  int m_end = ((const int*)(ws + WS_OFFSETS))[e] + ((const int*)(ws + WS_COUNTS))[e];
  int m_cnt = min(128, m_end - m_start);
  int n0 = blockIdx.x * 128;
  const bf16_t* Hbuf = (const bf16_t*)(ws + WS_HBUF);

  f32x4 acc[4][4];
  f32x4 z = {0.f, 0.f, 0.f, 0.f};
#pragma unroll
  for (int i = 0; i < 4; ++i)
#pragma unroll
    for (int j = 0; j < 4; ++j) acc[i][j] = z;

  int lane = tid & 63, wave = tid >> 6;
  int wm = wave >> 1, wn = wave & 1;
  int lr = lane & 15, quad = lane >> 4;
  int pk = (tid & 15) * 2, pn = (tid >> 4) * 8;
  const float* bBase = wo + ((size_t)e * DH + pk) * DM + n0 + pn;

  int aRow[2], aKc[2];
  const bf16_t* aPtr[2];
#pragma unroll
  for (int h = 0; h < 2; ++h) {
    int c = tid + h * 256;
    aRow[h] = c >> 2; aKc[h] = (c & 3) * 8;
    int hrow = m_start + min(aRow[h], m_cnt - 1);
    aPtr[h] = Hbuf + (size_t)hrow * DH + aKc[h];
  }

  int4 aR[2]; float4 bR[4];
#define G2_LOAD(k0)                                                  \
  {                                                                  \
    _Pragma("unroll")                                                \
    for (int h = 0; h < 2; ++h) aR[h] = *(const int4*)(aPtr[h] + (k0)); \
    const float* src = bBase + (size_t)(k0) * DM;                    \
    bR[0] = *(const float4*)src;                                     \
    bR[1] = *(const float4*)(src + 4);                               \
    bR[2] = *(const float4*)(src + DM);                              \
    bR[3] = *(const float4*)(src + DM + 4);                          \
  }

  G2_LOAD(0);
  for (int kt = 0; kt < DH / 32; ++kt) {
    __syncthreads();
#pragma unroll
    for (int h = 0; h < 2; ++h)
      *(int4*)&As[aRow[h] * PITCH + aKc[h]] = aR[h];
    {
      float av[8] = {bR[0].x, bR[0].y, bR[0].z, bR[0].w, bR[1].x, bR[1].y, bR[1].z, bR[1].w};
      float bv[8] = {bR[2].x, bR[2].y, bR[2].z, bR[2].w, bR[3].x, bR[3].y, bR[3].z, bR[3].w};
#pragma unroll
      for (int j = 0; j < 8; ++j) {
        unsigned int wv = (unsigned int)f2bf(av[j]) | ((unsigned int)f2bf(bv[j]) << 16);
        *(unsigned int*)&Bs[(pn + j) * PITCH + pk] = wv;
      }
    }
    __syncthreads();
    if (kt + 1 < DH / 32) G2_LOAD((kt + 1) * 32);
    bf16x8 a[4], b[4];
#pragma unroll
    for (int mt = 0; mt < 4; ++mt)
      a[mt] = *(const bf16x8*)&As[(wm * 64 + mt * 16 + lr) * PITCH + quad * 8];
#pragma unroll
    for (int nt = 0; nt < 4; ++nt)
      b[nt] = *(const bf16x8*)&Bs[(wn * 64 + nt * 16 + lr) * PITCH + quad * 8];
#pragma unroll
    for (int mt = 0; mt < 4; ++mt)
#pragma unroll
      for (int nt = 0; nt < 4; ++nt)
        acc[mt][nt] = __builtin_amdgcn_mfma_f32_16x16x32_bf16(a[mt], b[nt], acc[mt][nt], 0, 0, 0);
  }
  bf16_t* Ypair = (bf16_t*)(ws + WS_YPAIR);
  const float* wts = (const float*)(ws + WS_WT_OF);
#pragma unroll
  for (int mt = 0; mt < 4; ++mt) {
    int growb = wm * 64 + mt * 16 + quad * 4;
#pragma unroll
    for (int nt = 0; nt < 4; ++nt) {
      int col = n0 + wn * 64 + nt * 16 + lr;
      float bov = bo[e * DM + col];
#pragma unroll
      for (int r = 0; r < 4; ++r) {
        int grow = growb + r;
        if (grow < m_cnt) {
          int slot = m_start + grow;
          Ypair[(size_t)slot * DM + col] = __float2bfloat16((acc[mt][nt][r] + bov) * wts[slot]);
        }
      }
    }
  }
}

// ---------------- combine: out[t] = Y[slot(t,0)] + Y[slot(t,1)]  (f32 out) ----------------
__global__ __launch_bounds__(256) void k_combine(const char* __restrict__ ws,
                                                 float* __restrict__ out) {
  int idx = blockIdx.x * 256 + threadIdx.x;          // 8 cols each
  int t = idx >> 7, c = (idx & 127) * 8;
  const int* slot_of = (const int*)(ws + WS_SLOT_OF);
  int s0 = slot_of[2 * t], s1 = slot_of[2 * t + 1];
  const unsigned short* Y = (const unsigned short*)(ws + WS_YPAIR);
  int4 ya = *(const int4*)(Y + (size_t)s0 * DM + c);
  int4 yb = *(const int4*)(Y + (size_t)s1 * DM + c);
  const unsigned short* pa = (const unsigned short*)&ya;
  const unsigned short* pb = (const unsigned short*)&yb;
  float res[8];
#pragma unroll
  for (int j = 0; j < 8; ++j) {
    res[j] = __uint_as_float((unsigned int)pa[j] << 16) +
             __uint_as_float((unsigned int)pb[j] << 16);
  }
  float4 o0 = {res[0], res[1], res[2], res[3]};
  float4 o1 = {res[4], res[5], res[6], res[7]};
  *(float4*)(out + (size_t)t * DM + c) = o0;
  *(float4*)(out + (size_t)t * DM + c + 4) = o1;
}

extern "C" void kernel_launch(void* const* d_in, const int* in_sizes, int n_in,
                              void* d_out, int out_size, void* d_ws, size_t ws_size,
                              hipStream_t stream) {
  const float* x  = (const float*)d_in[0];
  const float* rw = (const float*)d_in[1];
  const float* rb = (const float*)d_in[2];
  const float* w1 = (const float*)d_in[3];
  const float* b1 = (const float*)d_in[4];
  const float* w2 = (const float*)d_in[5];
  const float* b2 = (const float*)d_in[6];
  const float* wo = (const float*)d_in[7];
  const float* bo = (const float*)d_in[8];
  float* out = (float*)d_out;
  char* ws = (char*)d_ws;
  if (ws_size < WS_NEEDED) return;
  int big = ws_size >= WS_NEEDED_BIG;   // fast path needs ~295 MB

  hipMemsetAsync(d_ws, 0, 4096, stream);  // zero counts/psum/ntiles/cursor
  k_router<<<RT_BLOCKS, 256, 0, stream>>>(x, rw, rb, ws);
  k_scan<<<1, 64, 0, stream>>>(ws, out);
  k_fill<<<N_PAIRS / 256, 256, 0, stream>>>(ws);
  if (big) {
    k_cvt_x<<<(T_TOKENS * DM / 8) / 256, 256, 0, stream>>>(x, ws);
    k_transp<<<dim3(DH / 64, DM / 64, N_EXP), 256, 0, stream>>>(w1, ws + WS_W1T, DM, DH);
    k_transp<<<dim3(DH / 64, DM / 64, N_EXP), 256, 0, stream>>>(w2, ws + WS_W2T, DM, DH);
    k_transp<<<dim3(DM / 64, DH / 64, N_EXP), 256, 0, stream>>>(wo, ws + WS_WOT, DH, DM);
    k_gemm1_bf<<<dim3(DH / 64, MAX_TILES), 256, 0, stream>>>(b1, b2, ws);
    k_gemm2_bf<<<dim3(DM / 128, MAX_TILES), 256, 0, stream>>>(bo, ws);
  } else {
    k_gemm1<<<dim3(DH / 64, MAX_TILES), 256, 0, stream>>>(x, w1, b1, w2, b2, ws);
    k_gemm2<<<dim3(DM / 128, MAX_TILES), 256, 0, stream>>>(wo, bo, ws);
  }
  k_combine<<<(T_TOKENS * DM / 8) / 256, 256, 0, stream>>>(ws, out);
}

// Round 5
// 735.061 us; speedup vs baseline: 1.6316x; 1.0691x over previous
//
#include <hip/hip_runtime.h>
#include <hip/hip_bf16.h>
#include <stdint.h>

// SparseMOE on MI355X (gfx950). Inputs/outputs FLOAT32.
// R8: revert fast GEMMs to the R5-verified structure (BK=64, single LDS buffer,
//     128-B rows, chunk-XOR swizzle both sides; measured: 173 us gemm1, 0 bank
//     conflicts, MfmaUtil 37%, 792 TF ~ 90% of the m97-structure ceiling).
//     R6/R7's BK=32 2-phase double-buffer was structurally slower: __syncthreads
//     drains vmcnt(0) including the same-iteration prefetch -> full latency paid
//     per 16 MFMA (vs per 32 in R5) with half the loads in flight. Keep R6/R7's
//     independent wins: pitch-65 k_transp (2-way banks) and 256-block router.
//     Fallback to R3 f32-staging kernels if workspace < ~295 MB.

#define T_TOKENS 4096
#define DM 1024
#define DH 4096
#define N_EXP 8
#define N_PAIRS (T_TOKENS * 2)
#define MAX_TILES 96             // worst-case sum ceil(N_e/128) = 71

typedef __hip_bfloat16 bf16_t;
typedef __bf16 bf16x8 __attribute__((ext_vector_type(8)));   // MFMA A/B frag (4 VGPRs)
typedef float  f32x4  __attribute__((ext_vector_type(4)));   // MFMA C/D frag
typedef unsigned short ushort4v __attribute__((ext_vector_type(4)));

// ---- workspace layout (byte offsets) ----
#define WS_COUNTS   0        // int[8]   tokens per expert
#define WS_OFFSETS  32       // int[8]   exclusive scan
#define WS_PSUM     96       // float[8] sum of probs per expert
#define WS_NTILES   128      // int
#define WS_CURSOR   192      // int[8]   slot-assignment cursors (k_fill)
#define WS_TILE_E   256      // int[128] tile -> expert
#define WS_TILE_M0  768      // int[128] tile -> first slot
#define WS_E_OF     4096     // int[8192]   (t,k) -> expert
#define WS_W_OF     69632    // float[8192] (t,k) -> gate weight
#define WS_TOK_OF   102400   // int[8192]   slot -> token
#define WS_WT_OF    135168   // float[8192] slot -> gate weight
#define WS_SLOT_OF  167936   // int[8192]   (t,k) -> slot
#define WS_HBUF     (1u<<20)                              // bf16[8192][4096] = 64 MB
#define WS_YPAIR    (WS_HBUF + (size_t)N_PAIRS*DH*2)      // bf16[8192][1024] = 16 MB
#define WS_NEEDED   (WS_YPAIR + (size_t)N_PAIRS*DM*2)     // ~81 MB (fallback path)
// fast path: bf16 pre-converted operands
#define WS_XBF      WS_NEEDED                             // bf16[4096][1024] = 8 MB
#define WS_W1T      (WS_XBF + (size_t)T_TOKENS*DM*2)      // bf16[E][DH][DM] = 64 MB
#define WS_W2T      (WS_W1T + (size_t)N_EXP*DM*DH*2)      // bf16[E][DH][DM] = 64 MB
#define WS_WOT      (WS_W2T + (size_t)N_EXP*DM*DH*2)      // bf16[E][DM][DH] = 64 MB
#define WS_NEEDED_BIG (WS_WOT + (size_t)N_EXP*DM*DH*2)    // ~295 MB

#define PITCH 40   // LDS row pitch for fallback kernels

__device__ __forceinline__ unsigned short f2bf(float f) {
  bf16_t h = __float2bfloat16(f);   // RNE
  return *(unsigned short*)&h;
}

// async global->LDS, 16 B per lane. LDS dest = wave-uniform base + lane*16.
__device__ __forceinline__ void gload16(const void* g, void* l) {
  __builtin_amdgcn_global_load_lds(
      (const __attribute__((address_space(1))) unsigned int*)g,
      (__attribute__((address_space(3))) unsigned int*)l, 16, 0, 0);
}

// ---------------- router: 256 blocks x 256 thr; wave handles 4 tokens ----------------
#define RT_BLOCKS 256
#define RT_TPB (T_TOKENS / RT_BLOCKS)   // 16 tokens per block
#define RT_TPW (RT_TPB / 4)             // 4 tokens per wave

__global__ __launch_bounds__(256) void k_router(const float* __restrict__ x,
                                                const float* __restrict__ rw,
                                                const float* __restrict__ rb,
                                                char* __restrict__ ws) {
  __shared__ float s_psum[4][8];
  __shared__ unsigned long long s_hist[4];
  int tid = threadIdx.x, lane = tid & 63, wave = tid >> 6;
  int t0 = blockIdx.x * RT_TPB + wave * RT_TPW;
  int* e_of = (int*)(ws + WS_E_OF);
  float* w_of = (float*)(ws + WS_W_OF);

  float lpsum[8];
#pragma unroll
  for (int e = 0; e < 8; ++e) lpsum[e] = 0.f;
  unsigned long long lhist = 0ull;

  for (int tt = 0; tt < RT_TPW; ++tt) {
    int t = t0 + tt;
    float acc[8];
#pragma unroll
    for (int e = 0; e < 8; ++e) acc[e] = 0.f;
    const float* xr = x + (size_t)t * DM;
    for (int j = lane; j < DM; j += 64) {
      float xv = xr[j];
      float4 r01 = *(const float4*)(rw + j * 8);
      float4 r23 = *(const float4*)(rw + j * 8 + 4);
      acc[0] += xv * r01.x; acc[1] += xv * r01.y;
      acc[2] += xv * r01.z; acc[3] += xv * r01.w;
      acc[4] += xv * r23.x; acc[5] += xv * r23.y;
      acc[6] += xv * r23.z; acc[7] += xv * r23.w;
    }
#pragma unroll
    for (int m = 1; m < 64; m <<= 1) {
#pragma unroll
      for (int e = 0; e < 8; ++e) acc[e] += __shfl_xor(acc[e], m);
    }
    float mx = -1e30f;
#pragma unroll
    for (int e = 0; e < 8; ++e) { acc[e] += rb[e]; mx = fmaxf(mx, acc[e]); }
    float s = 0.f;
#pragma unroll
    for (int e = 0; e < 8; ++e) { acc[e] = __expf(acc[e] - mx); s += acc[e]; }
    float inv = 1.f / s;
#pragma unroll
    for (int e = 0; e < 8; ++e) { acc[e] *= inv; lpsum[e] += acc[e]; }
    int i1 = 0;
#pragma unroll
    for (int e = 1; e < 8; ++e) if (acc[e] > acc[i1]) i1 = e;
    int i2 = -1;
#pragma unroll
    for (int e = 0; e < 8; ++e) if (e != i1 && (i2 < 0 || acc[e] > acc[i2])) i2 = e;
    lhist += (1ull << (i1 * 8)) + (1ull << (i2 * 8));
    if (lane == 0) {
      e_of[2 * t] = i1; e_of[2 * t + 1] = i2;
      w_of[2 * t] = acc[i1]; w_of[2 * t + 1] = acc[i2];
    }
  }
  if (lane == 0) {
#pragma unroll
    for (int e = 0; e < 8; ++e) s_psum[wave][e] = lpsum[e];
    s_hist[wave] = lhist;
  }
  __syncthreads();
  if (tid < 8) {
    float p = s_psum[0][tid] + s_psum[1][tid] + s_psum[2][tid] + s_psum[3][tid];
    atomicAdd((float*)(ws + WS_PSUM) + tid, p);
    int c = 0;
#pragma unroll
    for (int w = 0; w < 4; ++w) c += (int)((s_hist[w] >> (tid * 8)) & 0xff);
    atomicAdd((int*)(ws + WS_COUNTS) + tid, c);
  }
}

// ---------------- scan: offsets, tile table, lb_loss ----------------
__global__ void k_scan(char* __restrict__ ws, float* __restrict__ out) {
  if (threadIdx.x == 0 && blockIdx.x == 0) {
    int* counts = (int*)(ws + WS_COUNTS);
    int* offs = (int*)(ws + WS_OFFSETS);
    int* te = (int*)(ws + WS_TILE_E);
    int* tm = (int*)(ws + WS_TILE_M0);
    int off = 0, nt = 0;
    for (int e = 0; e < 8; ++e) {
      offs[e] = off;
      for (int m0 = 0; m0 < counts[e]; m0 += 128) { te[nt] = e; tm[nt] = off + m0; ++nt; }
      off += counts[e];
    }
    *(int*)(ws + WS_NTILES) = nt;
    float* psum = (float*)(ws + WS_PSUM);
    float lb = 0.f;
    for (int e = 0; e < 8; ++e)
      lb += ((float)counts[e] / (float)T_TOKENS) * (psum[e] / (float)T_TOKENS);
    lb *= 0.01f * 8.f;
    out[(size_t)T_TOKENS * DM] = lb;
  }
}

// ---------------- fill: (t,k) -> slot via block-level ranking ----------------
__global__ __launch_bounds__(256) void k_fill(char* __restrict__ ws) {
  __shared__ int hist[8];
  __shared__ int base[8];
  int tid = threadIdx.x;
  int i = blockIdx.x * 256 + tid;
  if (tid < 8) hist[tid] = 0;
  __syncthreads();
  int e = ((const int*)(ws + WS_E_OF))[i];
  int rank = atomicAdd(&hist[e], 1);
  __syncthreads();
  if (tid < 8) base[tid] = atomicAdd((int*)(ws + WS_CURSOR) + tid, hist[tid]);
  __syncthreads();
  int slot = ((const int*)(ws + WS_OFFSETS))[e] + base[e] + rank;
  ((int*)(ws + WS_TOK_OF))[slot] = i >> 1;
  ((float*)(ws + WS_WT_OF))[slot] = ((const float*)(ws + WS_W_OF))[i];
  ((int*)(ws + WS_SLOT_OF))[i] = slot;
}

// ---------------- pre-pass: x f32 -> bf16 ----------------
__global__ __launch_bounds__(256) void k_cvt_x(const float* __restrict__ x,
                                               char* __restrict__ ws) {
  int i = blockIdx.x * 256 + threadIdx.x;          // 8 elems each
  const float* s = x + (size_t)i * 8;
  float4 a = *(const float4*)s;
  float4 b = *(const float4*)(s + 4);
  uint4 v;
  v.x = (unsigned)f2bf(a.x) | ((unsigned)f2bf(a.y) << 16);
  v.y = (unsigned)f2bf(a.z) | ((unsigned)f2bf(a.w) << 16);
  v.z = (unsigned)f2bf(b.x) | ((unsigned)f2bf(b.y) << 16);
  v.w = (unsigned)f2bf(b.z) | ((unsigned)f2bf(b.w) << 16);
  *(uint4*)(ws + WS_XBF + (size_t)i * 16) = v;
}

// ---------------- pre-pass: transpose-convert [E][K][N] f32 -> [E][N][K] bf16 ------
// 64x64 tile per block, 256 threads. Pitch 65 (odd): both LDS sides 2-way (free).
__global__ __launch_bounds__(256) void k_transp(const float* __restrict__ in,
                                                char* __restrict__ outc,
                                                int K, int N) {
  __shared__ float tile[64][65];   // odd pitch: row+16 stride not bank-aliased
  int e = blockIdx.z;
  int k0 = blockIdx.y * 64, n0 = blockIdx.x * 64;
  int tid = threadIdx.x;
  const float* src = in + ((size_t)e * K + k0) * N + n0;
  int row = tid >> 2, c4 = (tid & 3) * 16;
  float4 v[4];
#pragma unroll
  for (int j = 0; j < 4; ++j)
    v[j] = *(const float4*)(src + (size_t)row * N + c4 + j * 4);
#pragma unroll
  for (int j = 0; j < 4; ++j) {   // scalar stores: banks (row + c4 + idx)%32 -> 2-way
    tile[row][c4 + 4 * j]     = v[j].x;
    tile[row][c4 + 4 * j + 1] = v[j].y;
    tile[row][c4 + 4 * j + 2] = v[j].z;
    tile[row][c4 + 4 * j + 3] = v[j].w;
  }
  __syncthreads();
  int n = tid >> 2, kc = (tid & 3) * 16;
  unsigned int pk[8];
#pragma unroll
  for (int j = 0; j < 8; ++j) {   // reads: banks (kc+2j+n)%32 -> 2-way (was 4-way)
    unsigned int lo = f2bf(tile[kc + 2 * j][n]);
    unsigned int hi = f2bf(tile[kc + 2 * j + 1][n]);
    pk[j] = lo | (hi << 16);
  }
  char* dst = outc + ((size_t)e * K * N + (size_t)(n0 + n) * K + k0 + kc) * 2;
  uint4 v0 = {pk[0], pk[1], pk[2], pk[3]};
  uint4 v1 = {pk[4], pk[5], pk[6], pk[7]};
  *(uint4*)dst = v0;
  *(uint4*)(dst + 16) = v1;
}

// ---------------- GEMM1 (fast): H = (X@W1+b1) * silu(X@W2+b2), bf16 operands -------
// 256 thr = 4 waves (2x2), BM=128 tokens, BN=64 hidden cols (x2 matrices), BK=64.
// LDS linear [row][64] bf16 (128 B rows) staged via global_load_lds; chunk-XOR
// swizzle c'=c^(row&7) applied on the global SOURCE and on ds_read (rule #21).
// R5-verified: 173 us, bank conflicts 0, MfmaUtil 37%.
__global__ __launch_bounds__(256, 2) void k_gemm1_bf(const float* __restrict__ b1,
                                                     const float* __restrict__ b2,
                                                     char* __restrict__ ws) {
  __shared__ __align__(16) unsigned short As[128 * 64];
  __shared__ __align__(16) unsigned short Bs1[64 * 64];
  __shared__ __align__(16) unsigned short Bs2[64 * 64];
  __shared__ int tokLds[128];
  int tid = threadIdx.x;
  int tileIdx = blockIdx.y;
  if (tileIdx >= *(const int*)(ws + WS_NTILES)) return;
  int e = ((const int*)(ws + WS_TILE_E))[tileIdx];
  int m_start = ((const int*)(ws + WS_TILE_M0))[tileIdx];
  int m_end = ((const int*)(ws + WS_OFFSETS))[e] + ((const int*)(ws + WS_COUNTS))[e];
  int m_cnt = min(128, m_end - m_start);
  int n0 = blockIdx.x * 64;
  if (tid < 128) tokLds[tid] = ((const int*)(ws + WS_TOK_OF))[m_start + min(tid, m_cnt - 1)];
  __syncthreads();

  int lane = tid & 63, wave = tid >> 6;
  int wm = wave >> 1, wn = wave & 1;
  int lr = lane & 15, quad = lane >> 4;
  int lsub = lane >> 3;           // row-sub within each 8-row staging group
  int clog = (lane & 7) ^ lsub;   // logical chunk this lane stages (inverse swizzle)

  const char* xbf = ws + WS_XBF;
  const char* w1t = ws + WS_W1T + (size_t)e * DM * DH * 2;
  const char* w2t = ws + WS_W2T + (size_t)e * DM * DH * 2;

  const char* srcA[4];
#pragma unroll
  for (int i = 0; i < 4; ++i) {
    int r = (wave * 4 + i) * 8 + lsub;   // row in [0,128)
    srcA[i] = xbf + (size_t)tokLds[r] * (DM * 2) + clog * 16;
  }
  const char* srcB1[2];
  const char* srcB2[2];
#pragma unroll
  for (int i = 0; i < 2; ++i) {
    int r = (wave * 2 + i) * 8 + lsub;   // row in [0,64)
    srcB1[i] = w1t + (size_t)(n0 + r) * (DM * 2) + clog * 16;
    srcB2[i] = w2t + (size_t)(n0 + r) * (DM * 2) + clog * 16;
  }

  f32x4 acc1[4][2], acc2[4][2];
  f32x4 z = {0.f, 0.f, 0.f, 0.f};
#pragma unroll
  for (int i = 0; i < 4; ++i)
#pragma unroll
    for (int j = 0; j < 2; ++j) { acc1[i][j] = z; acc2[i][j] = z; }

  for (int kt = 0; kt < DM / 64; ++kt) {
    int kb = kt * 128;   // byte advance per K-tile (64 bf16)
#pragma unroll
    for (int i = 0; i < 4; ++i)
      gload16(srcA[i] + kb, &As[(wave * 4 + i) * 512]);
#pragma unroll
    for (int i = 0; i < 2; ++i) {
      gload16(srcB1[i] + kb, &Bs1[(wave * 2 + i) * 512]);
      gload16(srcB2[i] + kb, &Bs2[(wave * 2 + i) * 512]);
    }
    __syncthreads();   // drains vmcnt(0): staged tile visible
#pragma unroll
    for (int s = 0; s < 2; ++s) {
      int sw = (((s * 4 + quad) ^ (lr & 7)) << 3);
      bf16x8 a[4], f1[2], f2v[2];
#pragma unroll
      for (int mt = 0; mt < 4; ++mt)
        a[mt] = *(const bf16x8*)&As[(wm * 64 + mt * 16 + lr) * 64 + sw];
#pragma unroll
      for (int nt = 0; nt < 2; ++nt) {
        int off = (wn * 32 + nt * 16 + lr) * 64 + sw;
        f1[nt]  = *(const bf16x8*)&Bs1[off];
        f2v[nt] = *(const bf16x8*)&Bs2[off];
      }
#pragma unroll
      for (int mt = 0; mt < 4; ++mt)
#pragma unroll
        for (int nt = 0; nt < 2; ++nt) {
          acc1[mt][nt] = __builtin_amdgcn_mfma_f32_16x16x32_bf16(a[mt], f1[nt],  acc1[mt][nt], 0, 0, 0);
          acc2[mt][nt] = __builtin_amdgcn_mfma_f32_16x16x32_bf16(a[mt], f2v[nt], acc2[mt][nt], 0, 0, 0);
        }
    }
    __syncthreads();   // compute done before next-tile overwrite
  }
  // epilogue: h = (t1+b1) * silu(t2+b2)  -> Hbuf bf16
  bf16_t* Hbuf = (bf16_t*)(ws + WS_HBUF);
#pragma unroll
  for (int mt = 0; mt < 4; ++mt) {
    int growb = wm * 64 + mt * 16 + quad * 4;   // C/D: row=(lane>>4)*4+reg, col=lane&15
#pragma unroll
    for (int nt = 0; nt < 2; ++nt) {
      int col = n0 + wn * 32 + nt * 16 + lr;
      float b1v = b1[e * DH + col];
      float b2v = b2[e * DH + col];
#pragma unroll
      for (int r = 0; r < 4; ++r) {
        int grow = growb + r;
        if (grow < m_cnt) {
          float v1 = acc1[mt][nt][r] + b1v;
          float v2 = acc2[mt][nt][r] + b2v;
          float hh = v1 * (v2 / (1.f + __expf(-v2)));
          Hbuf[(size_t)(m_start + grow) * DH + col] = __float2bfloat16(hh);
        }
      }
    }
  }
}

// ---------------- GEMM2 (fast): Y = wt * (H@wo + bo), bf16 operands ----------------
// 256 thr = 4 waves (2x2), BM=128 slots, BN=128 model cols, BK=64, K=4096.
// R5-verified structure.
__global__ __launch_bounds__(256, 2) void k_gemm2_bf(const float* __restrict__ bo,
                                                     char* __restrict__ ws) {
  __shared__ __align__(16) unsigned short As[128 * 64];
  __shared__ __align__(16) unsigned short Bs[128 * 64];
  int tid = threadIdx.x;
  int tileIdx = blockIdx.y;
  if (tileIdx >= *(const int*)(ws + WS_NTILES)) return;
  int e = ((const int*)(ws + WS_TILE_E))[tileIdx];
  int m_start = ((const int*)(ws + WS_TILE_M0))[tileIdx];
  int m_end = ((const int*)(ws + WS_OFFSETS))[e] + ((const int*)(ws + WS_COUNTS))[e];
  int m_cnt = min(128, m_end - m_start);
  int n0 = blockIdx.x * 128;

  int lane = tid & 63, wave = tid >> 6;
  int wm = wave >> 1, wn = wave & 1;
  int lr = lane & 15, quad = lane >> 4;
  int lsub = lane >> 3;
  int clog = (lane & 7) ^ lsub;

  const char* hb = ws + WS_HBUF;
  const char* wot = ws + WS_WOT + (size_t)e * DM * DH * 2;

  const char* srcA[4];
  const char* srcB[4];
#pragma unroll
  for (int i = 0; i < 4; ++i) {
    int r = (wave * 4 + i) * 8 + lsub;                  // row in [0,128)
    int hrow = m_start + min(r, m_cnt - 1);             // clamp: stay in written Hbuf
    srcA[i] = hb + (size_t)hrow * (DH * 2) + clog * 16;
    srcB[i] = wot + (size_t)(n0 + r) * (DH * 2) + clog * 16;
  }

  f32x4 acc[4][4];
  f32x4 z = {0.f, 0.f, 0.f, 0.f};
#pragma unroll
  for (int i = 0; i < 4; ++i)
#pragma unroll
    for (int j = 0; j < 4; ++j) acc[i][j] = z;

  for (int kt = 0; kt < DH / 64; ++kt) {
    int kb = kt * 128;
#pragma unroll
    for (int i = 0; i < 4; ++i) {
      gload16(srcA[i] + kb, &As[(wave * 4 + i) * 512]);
      gload16(srcB[i] + kb, &Bs[(wave * 4 + i) * 512]);
    }
    __syncthreads();
#pragma unroll
    for (int s = 0; s < 2; ++s) {
      int sw = (((s * 4 + quad) ^ (lr & 7)) << 3);
      bf16x8 a[4], b[4];
#pragma unroll
      for (int mt = 0; mt < 4; ++mt)
        a[mt] = *(const bf16x8*)&As[(wm * 64 + mt * 16 + lr) * 64 + sw];
#pragma unroll
      for (int nt = 0; nt < 4; ++nt)
        b[nt] = *(const bf16x8*)&Bs[(wn * 64 + nt * 16 + lr) * 64 + sw];
#pragma unroll
      for (int mt = 0; mt < 4; ++mt)
#pragma unroll
        for (int nt = 0; nt < 4; ++nt)
          acc[mt][nt] = __builtin_amdgcn_mfma_f32_16x16x32_bf16(a[mt], b[nt], acc[mt][nt], 0, 0, 0);
    }
    __syncthreads();
  }
  bf16_t* Ypair = (bf16_t*)(ws + WS_YPAIR);
  const float* wts = (const float*)(ws + WS_WT_OF);
#pragma unroll
  for (int mt = 0; mt < 4; ++mt) {
    int growb = wm * 64 + mt * 16 + quad * 4;
#pragma unroll
    for (int nt = 0; nt < 4; ++nt) {
      int col = n0 + wn * 64 + nt * 16 + lr;
      float bov = bo[e * DM + col];
#pragma unroll
      for (int r = 0; r < 4; ++r) {
        int grow = growb + r;
        if (grow < m_cnt) {
          int slot = m_start + grow;
          Ypair[(size_t)slot * DM + col] = __float2bfloat16((acc[mt][nt][r] + bov) * wts[slot]);
        }
      }
    }
  }
}

// ================= fallback (R3) GEMMs: f32 operands, reg-stage + cvt =================
__global__ __launch_bounds__(256, 2) void k_gemm1(const float* __restrict__ x,
                                                  const float* __restrict__ w1,
                                                  const float* __restrict__ b1,
                                                  const float* __restrict__ w2,
                                                  const float* __restrict__ b2,
                                                  char* __restrict__ ws) {
  __shared__ __align__(16) unsigned short As[128 * PITCH];
  __shared__ __align__(16) unsigned short Bs1[64 * PITCH];
  __shared__ __align__(16) unsigned short Bs2[64 * PITCH];
  __shared__ int tokLds[128];
  int tid = threadIdx.x;
  int tileIdx = blockIdx.y;
  if (tileIdx >= *(const int*)(ws + WS_NTILES)) return;
  int e = ((const int*)(ws + WS_TILE_E))[tileIdx];
  int m_start = ((const int*)(ws + WS_TILE_M0))[tileIdx];
  int m_end = ((const int*)(ws + WS_OFFSETS))[e] + ((const int*)(ws + WS_COUNTS))[e];
  int m_cnt = min(128, m_end - m_start);
  int n0 = blockIdx.x * 64;
  if (tid < 128) tokLds[tid] = ((const int*)(ws + WS_TOK_OF))[m_start + min(tid, m_cnt - 1)];
  __syncthreads();

  f32x4 acc1[4][2], acc2[4][2];
  f32x4 z = {0.f, 0.f, 0.f, 0.f};
#pragma unroll
  for (int i = 0; i < 4; ++i)
#pragma unroll
    for (int j = 0; j < 2; ++j) { acc1[i][j] = z; acc2[i][j] = z; }

  int lane = tid & 63, wave = tid >> 6;
  int wm = wave >> 1, wn = wave & 1;
  int lr = lane & 15, quad = lane >> 4;
  int q = tid & 127, mat = tid >> 7;
  int pk = (q & 15) * 2, pn = (q >> 4) * 8;
  const float* Wm = mat ? w2 : w1;
  unsigned short* BsM = mat ? Bs2 : Bs1;
  const float* bBase = Wm + ((size_t)e * DM + pk) * DH + n0 + pn;

  int aRow[4], aKc[4];
  const float* aPtr[4];
#pragma unroll
  for (int h = 0; h < 4; ++h) {
    int c = tid + h * 256;
    aRow[h] = c >> 3; aKc[h] = (c & 7) * 4;
    aPtr[h] = x + (size_t)tokLds[aRow[h]] * DM + aKc[h];
  }

  float4 aR[4], bR[4];
#define G1_LOAD(k0)                                                  \
  {                                                                  \
    _Pragma("unroll")                                                \
    for (int h = 0; h < 4; ++h) aR[h] = *(const float4*)(aPtr[h] + (k0)); \
    const float* src = bBase + (size_t)(k0) * DH;                    \
    bR[0] = *(const float4*)src;                                     \
    bR[1] = *(const float4*)(src + 4);                               \
    bR[2] = *(const float4*)(src + DH);                              \
    bR[3] = *(const float4*)(src + DH + 4);                          \
  }

  G1_LOAD(0);
  for (int kt = 0; kt < DM / 32; ++kt) {
    __syncthreads();
#pragma unroll
    for (int h = 0; h < 4; ++h) {
      ushort4v wv = { f2bf(aR[h].x), f2bf(aR[h].y), f2bf(aR[h].z), f2bf(aR[h].w) };
      *(ushort4v*)&As[aRow[h] * PITCH + aKc[h]] = wv;
    }
    {
      float av[8] = {bR[0].x, bR[0].y, bR[0].z, bR[0].w, bR[1].x, bR[1].y, bR[1].z, bR[1].w};
      float bv[8] = {bR[2].x, bR[2].y, bR[2].z, bR[2].w, bR[3].x, bR[3].y, bR[3].z, bR[3].w};
#pragma unroll
      for (int j = 0; j < 8; ++j) {
        unsigned int wv = (unsigned int)f2bf(av[j]) | ((unsigned int)f2bf(bv[j]) << 16);
        *(unsigned int*)&BsM[(pn + j) * PITCH + pk] = wv;
      }
    }
    __syncthreads();
    if (kt + 1 < DM / 32) G1_LOAD((kt + 1) * 32);
    bf16x8 a[4], f1[2], f2v[2];
#pragma unroll
    for (int mt = 0; mt < 4; ++mt)
      a[mt] = *(const bf16x8*)&As[(wm * 64 + mt * 16 + lr) * PITCH + quad * 8];
#pragma unroll
    for (int nt = 0; nt < 2; ++nt) {
      f1[nt]  = *(const bf16x8*)&Bs1[(wn * 32 + nt * 16 + lr) * PITCH + quad * 8];
      f2v[nt] = *(const bf16x8*)&Bs2[(wn * 32 + nt * 16 + lr) * PITCH + quad * 8];
    }
#pragma unroll
    for (int mt = 0; mt < 4; ++mt)
#pragma unroll
      for (int nt = 0; nt < 2; ++nt) {
        acc1[mt][nt] = __builtin_amdgcn_mfma_f32_16x16x32_bf16(a[mt], f1[nt],  acc1[mt][nt], 0, 0, 0);
        acc2[mt][nt] = __builtin_amdgcn_mfma_f32_16x16x32_bf16(a[mt], f2v[nt], acc2[mt][nt], 0, 0, 0);
      }
  }
  bf16_t* Hbuf = (bf16_t*)(ws + WS_HBUF);
#pragma unroll
  for (int mt = 0; mt < 4; ++mt) {
    int growb = wm * 64 + mt * 16 + quad * 4;
#pragma unroll
    for (int nt = 0; nt < 2; ++nt) {
      int col = n0 + wn * 32 + nt * 16 + lr;
      float b1v = b1[e * DH + col];
      float b2v = b2[e * DH + col];
#pragma unroll
      for (int r = 0; r < 4; ++r) {
        int grow = growb + r;
        if (grow < m_cnt) {
          float v1 = acc1[mt][nt][r] + b1v;
          float v2 = acc2[mt][nt][r] + b2v;
          float hh = v1 * (v2 / (1.f + __expf(-v2)));
          Hbuf[(size_t)(m_start + grow) * DH + col] = __float2bfloat16(hh);
        }
      }
    }
  }
}

__global__ __launch_bounds__(256, 2) void k_gemm2(const float* __restrict__ wo,
                                                  const float* __restrict__ bo,
                                                  char* __restrict__ ws) {
  __shared__ __align__(16) unsigned short As[128 * PITCH];
  __shared__ __align__(16) unsigned short Bs[128 * PITCH];
  int tid = threadIdx.x;
  int tileIdx = blockIdx.y;
  if (tileIdx >= *(const int*)(ws + WS_NTILES)) return;
  int e = ((const int*)(ws + WS_TILE_E))[tileIdx];
  int m_start = ((const int*)(ws + WS_TILE_M0))[tileIdx];
  int m_end = ((const int*)(ws + WS_OFFSETS))[e] + ((const int*)(ws + WS_COUNTS))[e];
  int m_cnt = min(128, m_end - m_start);
  int n0 = blockIdx.x * 128;
  const bf16_t* Hbuf = (const bf16_t*)(ws + WS_HBUF);

  f32x4 acc[4][4];
  f32x4 z = {0.f, 0.f, 0.f, 0.f};
#pragma unroll
  for (int i = 0; i < 4; ++i)
#pragma unroll
    for (int j = 0; j < 4; ++j) acc[i][j] = z;

  int lane = tid & 63, wave = tid >> 6;
  int wm = wave >> 1, wn = wave & 1;
  int lr = lane & 15, quad = lane >> 4;
  int pk = (tid & 15) * 2, pn = (tid >> 4) * 8;
  const float* bBase = wo + ((size_t)e * DH + pk) * DM + n0 + pn;

  int aRow[2], aKc[2];
  const bf16_t* aPtr[2];
#pragma unroll
  for (int h = 0; h < 2; ++h) {
    int c = tid + h * 256;
    aRow[h] = c >> 2; aKc[h] = (c & 3) * 8;
    int hrow = m_start + min(aRow[h], m_cnt - 1);
    aPtr[h] = Hbuf + (size_t)hrow * DH + aKc[h];
  }

  int4 aR[2]; float4 bR[4];
#define G2_LOAD(k0)                                                  \
  {                                                                  \
    _Pragma("unroll")                                                \
    for (int h = 0; h < 2; ++h) aR[h] = *(const int4*)(aPtr[h] + (k0)); \
    const float* src = bBase + (size_t)(k0) * DM;                    \
    bR[0] = *(const float4*)src;                                     \
    bR[1] = *(const float4*)(src + 4);                               \
    bR[2] = *(const float4*)(src + DM);                              \
    bR[3] = *(const float4*)(src + DM + 4);                          \
  }

  G2_LOAD(0);
  for (int kt = 0; kt < DH / 32; ++kt) {
    __syncthreads();
#pragma unroll
    for (int h = 0; h < 2; ++h)
      *(int4*)&As[aRow[h] * PITCH + aKc[h]] = aR[h];
    {
      float av[8] = {bR[0].x, bR[0].y, bR[0].z, bR[0].w, bR[1].x, bR[1].y, bR[1].z, bR[1].w};
      float bv[8] = {bR[2].x, bR[2].y, bR[2].z, bR[2].w, bR[3].x, bR[3].y, bR[3].z, bR[3].w};
#pragma unroll
      for (int j = 0; j < 8; ++j) {
        unsigned int wv = (unsigned int)f2bf(av[j]) | ((unsigned int)f2bf(bv[j]) << 16);
        *(unsigned int*)&Bs[(pn + j) * PITCH + pk] = wv;
      }
    }
    __syncthreads();
    if (kt + 1 < DH / 32) G2_LOAD((kt + 1) * 32);
    bf16x8 a[4], b[4];
#pragma unroll
    for (int mt = 0; mt < 4; ++mt)
      a[mt] = *(const bf16x8*)&As[(wm * 64 + mt * 16 + lr) * PITCH + quad * 8];
#pragma unroll
    for (int nt = 0; nt < 4; ++nt)
      b[nt] = *(const bf16x8*)&Bs[(wn * 64 + nt * 16 + lr) * PITCH + quad * 8];
#pragma unroll
    for (int mt = 0; mt < 4; ++mt)
#pragma unroll
      for (int nt = 0; nt < 4; ++nt)
        acc[mt][nt] = __builtin_amdgcn_mfma_f32_16x16x32_bf16(a[mt], b[nt], acc[mt][nt], 0, 0, 0);
  }
  bf16_t* Ypair = (bf16_t*)(ws + WS_YPAIR);
  const float* wts = (const float*)(ws + WS_WT_OF);
#pragma unroll
  for (int mt = 0; mt < 4; ++mt) {
    int growb = wm * 64 + mt * 16 + quad * 4;
#pragma unroll
    for (int nt = 0; nt < 4; ++nt) {
      int col = n0 + wn * 64 + nt * 16 + lr;
      float bov = bo[e * DM + col];
#pragma unroll
      for (int r = 0; r < 4; ++r) {
        int grow = growb + r;
        if (grow < m_cnt) {
          int slot = m_start + grow;
          Ypair[(size_t)slot * DM + col] = __float2bfloat16((acc[mt][nt][r] + bov) * wts[slot]);
        }
      }
    }
  }
}

// ---------------- combine: out[t] = Y[slot(t,0)] + Y[slot(t,1)]  (f32 out) ----------------
__global__ __launch_bounds__(256) void k_combine(const char* __restrict__ ws,
                                                 float* __restrict__ out) {
  int idx = blockIdx.x * 256 + threadIdx.x;          // 8 cols each
  int t = idx >> 7, c = (idx & 127) * 8;
  const int* slot_of = (const int*)(ws + WS_SLOT_OF);
  int s0 = slot_of[2 * t], s1 = slot_of[2 * t + 1];
  const unsigned short* Y = (const unsigned short*)(ws + WS_YPAIR);
  int4 ya = *(const int4*)(Y + (size_t)s0 * DM + c);
  int4 yb = *(const int4*)(Y + (size_t)s1 * DM + c);
  const unsigned short* pa = (const unsigned short*)&ya;
  const unsigned short* pb = (const unsigned short*)&yb;
  float res[8];
#pragma unroll
  for (int j = 0; j < 8; ++j) {
    res[j] = __uint_as_float((unsigned int)pa[j] << 16) +
             __uint_as_float((unsigned int)pb[j] << 16);
  }
  float4 o0 = {res[0], res[1], res[2], res[3]};
  float4 o1 = {res[4], res[5], res[6], res[7]};
  *(float4*)(out + (size_t)t * DM + c) = o0;
  *(float4*)(out + (size_t)t * DM + c + 4) = o1;
}

extern "C" void kernel_launch(void* const* d_in, const int* in_sizes, int n_in,
                              void* d_out, int out_size, void* d_ws, size_t ws_size,
                              hipStream_t stream) {
  const float* x  = (const float*)d_in[0];
  const float* rw = (const float*)d_in[1];
  const float* rb = (const float*)d_in[2];
  const float* w1 = (const float*)d_in[3];
  const float* b1 = (const float*)d_in[4];
  const float* w2 = (const float*)d_in[5];
  const float* b2 = (const float*)d_in[6];
  const float* wo = (const float*)d_in[7];
  const float* bo = (const float*)d_in[8];
  float* out = (float*)d_out;
  char* ws = (char*)d_ws;
  if (ws_size < WS_NEEDED) return;
  int big = ws_size >= WS_NEEDED_BIG;   // fast path needs ~295 MB

  hipMemsetAsync(d_ws, 0, 4096, stream);  // zero counts/psum/ntiles/cursor
  k_router<<<RT_BLOCKS, 256, 0, stream>>>(x, rw, rb, ws);
  k_scan<<<1, 64, 0, stream>>>(ws, out);
  k_fill<<<N_PAIRS / 256, 256, 0, stream>>>(ws);
  if (big) {
    k_cvt_x<<<(T_TOKENS * DM / 8) / 256, 256, 0, stream>>>(x, ws);
    k_transp<<<dim3(DH / 64, DM / 64, N_EXP), 256, 0, stream>>>(w1, ws + WS_W1T, DM, DH);
    k_transp<<<dim3(DH / 64, DM / 64, N_EXP), 256, 0, stream>>>(w2, ws + WS_W2T, DM, DH);
    k_transp<<<dim3(DM / 64, DH / 64, N_EXP), 256, 0, stream>>>(wo, ws + WS_WOT, DH, DM);
    k_gemm1_bf<<<dim3(DH / 64, MAX_TILES), 256, 0, stream>>>(b1, b2, ws);
    k_gemm2_bf<<<dim3(DM / 128, MAX_TILES), 256, 0, stream>>>(bo, ws);
  } else {
    k_gemm1<<<dim3(DH / 64, MAX_TILES), 256, 0, stream>>>(x, w1, b1, w2, b2, ws);
    k_gemm2<<<dim3(DM / 128, MAX_TILES), 256, 0, stream>>>(wo, bo, ws);
  }
  k_combine<<<(T_TOKENS * DM / 8) / 256, 256, 0, stream>>>(ws, out);
}